// Round 4
// baseline (636.402 us; speedup 1.0000x reference)
//
#include <hip/hip_runtime.h>

#define S 16
#define B 8
#define H 16
#define DH 64
#define D 1024
#define HD 1024          // H*DH
#define LC 8192
#define LMAX (LC + S)    // 8208
#define NCH 16           // L-chunks per (b,h)
#define CHT 512          // t rows per chunk
#define ST 32            // subtile rows staged in LDS
#define KPAD 68          // padded row length (floats), 16B-aligned

// ---- QKV projection: 4 rows/block, scalar-uniform x, deep-unrolled W stream,
//      XCD co-location: all 32 rowgroups of one (mat,chunk) on one XCD -------
// grid = 512 (12 pairs x 32 rowgroups, XCD-packed; extras exit)
__global__ __launch_bounds__(256) void proj_qkv(const float* __restrict__ x,
        const float* __restrict__ Wq, const float* __restrict__ Wk,
        const float* __restrict__ Wv,
        float* __restrict__ q_ws, float* __restrict__ newk, float* __restrict__ newv)
{
    int bx = blockIdx.x;
    int xcd = bx & 7, q = bx >> 3;
    int p, rg;
    if (q < 32) { p = xcd;     rg = q; }
    else        { p = 8 + xcd; rg = q - 32; if (p >= 12) return; }
    int mat = p >> 2, chunk = p & 3;
    int o = chunk * 256 + threadIdx.x;
    const float* W  = (mat == 0) ? Wq : ((mat == 1) ? Wk : Wv);
    const float* xr = x + (size_t)rg * 4 * D;

    float a0 = 0.f, a1 = 0.f, a2 = 0.f, a3 = 0.f;
    #pragma unroll 32
    for (int d = 0; d < D; ++d) {
        float w = W[(size_t)d * HD + o];       // coalesced 256B wave-loads
        a0 += xr[d] * w;                       // uniform -> scalar loads
        a1 += xr[D + d] * w;
        a2 += xr[2 * D + d] * w;
        a3 += xr[3 * D + d] * w;
    }
    float acc[4] = {a0, a1, a2, a3};
    #pragma unroll
    for (int i = 0; i < 4; ++i) {
        int row = rg * 4 + i;
        int s = row >> 3, b = row & 7;
        if (mat == 0) {
            q_ws[(size_t)row * HD + o] = acc[i];
        } else {
            float* dst = (mat == 1) ? newk : newv;
            dst[(size_t)((LC + s) * B + b) * HD + o] = acc[i];
        }
    }
}

// ---- fused cache-copy + flash attention (R2 structure, ST=32) -------------
// grid = B*H*NCH (bh*16 + chunk), block = 256 (4 waves)
// wave sg owns s in [4sg,4sg+4); lanes 0-31 own s {4sg,4sg+1}, lanes 32-63 own {4sg+2,4sg+3}
__global__ __launch_bounds__(256, 4) void attn_fused(const float* __restrict__ q_ws,
        const float* __restrict__ cache_k, const float* __restrict__ cache_v,
        float* __restrict__ newk, float* __restrict__ newv,
        float* __restrict__ m_part, float* __restrict__ l_part,
        float* __restrict__ pv_part)
{
    __shared__ float Ks[ST][KPAD];
    __shared__ float Vs[ST][KPAD];
    __shared__ float qs[S][KPAD];
    __shared__ float sc[S][ST];

    int chunk = blockIdx.x & 15;
    int bh    = blockIdx.x >> 4;
    int h = bh & 15, b = bh >> 4;
    int tid = threadIdx.x, lane = tid & 63, sg = tid >> 6;
    int r = tid >> 4, c = tid & 15;
    int t = lane & 31, half = lane >> 5;
    int sA = sg * 4 + half * 2;              // my two s rows: sA, sA+1

    // q tile (16x64) into LDS (covered by first barrier)
    *(float4*)&qs[r][c * 4] =
        *(const float4*)(q_ws + ((size_t)(r * B + b)) * HD + h * DH + c * 4);

    float m_prev[2] = {-1e30f, -1e30f};
    float l_acc[4]  = {0.f, 0.f, 0.f, 0.f};
    float pv_acc[4] = {0.f, 0.f, 0.f, 0.f};

    auto compute_tile = [&](int t0, int nrows) {
        // scores: 2 s-rows x my t position
        float a0 = 0.f, a1 = 0.f;
        #pragma unroll
        for (int i = 0; i < 16; ++i) {
            float4 k4 = *(float4*)&Ks[t][i * 4];
            float4 q0 = *(float4*)&qs[sA][i * 4];
            float4 q1 = *(float4*)&qs[sA + 1][i * 4];
            a0 += k4.x * q0.x + k4.y * q0.y + k4.z * q0.z + k4.w * q0.w;
            a1 += k4.x * q1.x + k4.y * q1.y + k4.z * q1.z + k4.w * q1.w;
        }
        a0 *= 0.125f; a1 *= 0.125f;
        int tg = t0 + t;
        if (t >= nrows || tg > LC + sA)     a0 = -1e30f;
        if (t >= nrows || tg > LC + sA + 1) a1 = -1e30f;

        // max-reduce within each 32-lane half
        float m0 = a0, m1 = a1;
        #pragma unroll
        for (int msk = 16; msk; msk >>= 1) {
            m0 = fmaxf(m0, __shfl_xor(m0, msk));
            m1 = fmaxf(m1, __shfl_xor(m1, msk));
        }
        float mn0 = fmaxf(m_prev[0], m0), mn1 = fmaxf(m_prev[1], m1);
        float sf0 = __expf(m_prev[0] - mn0), sf1 = __expf(m_prev[1] - mn1);
        m_prev[0] = mn0; m_prev[1] = mn1;
        sc[sA][t]     = __expf(a0 - mn0);
        sc[sA + 1][t] = __expf(a1 - mn1);

        // gather all 4 scale factors of this wave (partner half via shfl)
        float sf0o = __shfl_xor(sf0, 32), sf1o = __shfl_xor(sf1, 32);
        float sfj0 = half ? sf0o : sf0;   // s = 4sg+0
        float sfj1 = half ? sf1o : sf1;   // s = 4sg+1
        float sfj2 = half ? sf0  : sf0o;  // s = 4sg+2
        float sfj3 = half ? sf1  : sf1o;  // s = 4sg+3

        // own-wave sc writes -> own-wave sc reads: fence (+ pin scheduler)
        asm volatile("s_waitcnt lgkmcnt(0)" ::: "memory");
        __builtin_amdgcn_sched_barrier(0);

        l_acc[0] *= sfj0; pv_acc[0] *= sfj0;
        l_acc[1] *= sfj1; pv_acc[1] *= sfj1;
        l_acc[2] *= sfj2; pv_acc[2] *= sfj2;
        l_acc[3] *= sfj3; pv_acc[3] *= sfj3;

        // PV: lane = d, 8 row-quads
        #pragma unroll
        for (int tt = 0; tt < ST / 4; ++tt) {
            float v0 = Vs[tt * 4 + 0][lane];
            float v1 = Vs[tt * 4 + 1][lane];
            float v2 = Vs[tt * 4 + 2][lane];
            float v3 = Vs[tt * 4 + 3][lane];
            #pragma unroll
            for (int j = 0; j < 4; ++j) {
                float4 pq = *(float4*)&sc[sg * 4 + j][tt * 4];
                pv_acc[j] += pq.x * v0 + pq.y * v1 + pq.z * v2 + pq.w * v3;
                l_acc[j]  += pq.x + pq.y + pq.z + pq.w;
            }
        }
    };

    int t0base = chunk * CHT;

    for (int it = 0; it < CHT / ST; ++it) {
        int t0 = t0base + it * ST;
        __syncthreads();   // prev tile's LDS readers done
        #pragma unroll
        for (int g = 0; g < 2; ++g) {
            size_t off = ((size_t)(t0 + r + 16 * g) * B + b) * HD + h * DH + c * 4;
            float4 k4 = *(const float4*)(cache_k + off);
            float4 v4 = *(const float4*)(cache_v + off);
            *(float4*)&Ks[r + 16 * g][c * 4] = k4;
            *(float4*)&Vs[r + 16 * g][c * 4] = v4;
            *(float4*)(newk + off) = k4;       // the cache copy
            *(float4*)(newv + off) = v4;
        }
        __syncthreads();   // staged data visible
        compute_tile(t0, ST);
    }

    if (chunk == NCH - 1) {   // tail: 16 new rows, already in newk/newv
        __syncthreads();
        {
            size_t off = ((size_t)(LC + r) * B + b) * HD + h * DH + c * 4;
            *(float4*)&Ks[r][c * 4] = *(const float4*)(newk + off);
            *(float4*)&Vs[r][c * 4] = *(const float4*)(newv + off);
        }
        __syncthreads();
        compute_tile(LC, S);
    }

    // emit partials
    int pi = blockIdx.x;
    #pragma unroll
    for (int j = 0; j < 4; ++j)
        pv_part[((size_t)pi * S + sg * 4 + j) * DH + lane] = pv_acc[j];
    if (t == 0) {                       // lane 0 and lane 32: running max of their 2 s
        m_part[pi * S + sA]     = m_prev[0];
        m_part[pi * S + sA + 1] = m_prev[1];
    }
    if (lane == 0) {                    // l_acc identical across lanes
        #pragma unroll
        for (int j = 0; j < 4; ++j) l_part[pi * S + sg * 4 + j] = l_acc[j];
    }
}

// ---- combine partials over chunks -> ctx ----------------------------------
__global__ __launch_bounds__(64) void combine(const float* __restrict__ m_part,
        const float* __restrict__ l_part, const float* __restrict__ pv_part,
        float* __restrict__ ctx)
{
    int s  = blockIdx.x & 15;
    int bh = blockIdx.x >> 4;
    int h = bh & 15, b = bh >> 4;
    int d = threadIdx.x;

    float M = -1e30f;
    #pragma unroll
    for (int cc = 0; cc < NCH; ++cc) M = fmaxf(M, m_part[(bh * NCH + cc) * S + s]);
    float L = 0.f, acc = 0.f;
    #pragma unroll
    for (int cc = 0; cc < NCH; ++cc) {
        int pi = bh * NCH + cc;
        float w = __expf(m_part[pi * S + s] - M);
        L   += l_part[pi * S + s] * w;
        acc += w * pv_part[((size_t)pi * S + s) * DH + d];
    }
    ctx[((size_t)(s * B + b)) * HD + h * DH + d] = acc / L;
}

// ---- output projection: 2 rows/block, XCD co-location, deep unroll --------
// grid = 256 (4 chunks x 64 rowgroups; chunk c on XCDs {c, c+4})
__global__ __launch_bounds__(256) void proj_o(const float* __restrict__ ctx,
                                              const float* __restrict__ Wo,
                                              float* __restrict__ res)
{
    int bx = blockIdx.x;
    int chunk = bx & 3;
    int rg = ((bx >> 3) << 1) | ((bx >> 2) & 1);
    int o = chunk * 256 + threadIdx.x;
    const float* cr = ctx + (size_t)rg * 2 * HD;

    float a0 = 0.f, a1 = 0.f;
    #pragma unroll 32
    for (int d = 0; d < HD; ++d) {
        float w = Wo[(size_t)d * D + o];
        a0 += cr[d] * w;
        a1 += cr[HD + d] * w;
    }
    res[(size_t)(rg * 2) * D + o]     = a0;
    res[(size_t)(rg * 2 + 1) * D + o] = a1;
}

extern "C" void kernel_launch(void* const* d_in, const int* in_sizes, int n_in,
                              void* d_out, int out_size, void* d_ws, size_t ws_size,
                              hipStream_t stream)
{
    const float* x  = (const float*)d_in[0];
    const float* ck = (const float*)d_in[1];
    const float* cv = (const float*)d_in[2];
    const float* Wq = (const float*)d_in[3];
    const float* Wk = (const float*)d_in[4];
    const float* Wv = (const float*)d_in[5];
    const float* Wo = (const float*)d_in[6];

    float* out  = (float*)d_out;
    float* res  = out;                                   // (S,B,D)
    float* newk = out + (size_t)S * B * D;               // (L,B,H,DH)
    float* newv = newk + (size_t)LMAX * B * H * DH;

    float* q_ws    = (float*)d_ws;                            // S*B*HD
    float* ctx     = q_ws + (size_t)S * B * HD;
    float* m_part  = ctx + (size_t)S * B * HD;
    float* l_part  = m_part + (size_t)B * H * NCH * S;
    float* pv_part = l_part + (size_t)B * H * NCH * S;

    hipLaunchKernelGGL(proj_qkv, dim3(512), dim3(256), 0, stream,
                       x, Wq, Wk, Wv, q_ws, newk, newv);
    hipLaunchKernelGGL(attn_fused, dim3(B * H * NCH), dim3(256), 0, stream,
                       q_ws, ck, cv, newk, newv, m_part, l_part, pv_part);
    hipLaunchKernelGGL(combine, dim3(B * H * S), dim3(64), 0, stream,
                       m_part, l_part, pv_part, ctx);
    hipLaunchKernelGGL(proj_o, dim3(256), dim3(256), 0, stream,
                       ctx, Wo, res);
}

// Round 5
// 468.501 us; speedup vs baseline: 1.3584x; 1.3584x over previous
//
#include <hip/hip_runtime.h>

#define S 16
#define B 8
#define H 16
#define DH 64
#define D 1024
#define HD 1024          // H*DH
#define LC 8192
#define LMAX (LC + S)    // 8208
#define NCH 16           // L-chunks per (b,h)
#define CHT 512          // t rows per chunk
#define ST 64            // subtile rows staged in LDS
#define KPAD 68          // padded row length (floats), 16B-aligned

// ---- QKV projection: 4 rows/block, scalar-uniform x loads, coalesced W ----
// grid = 32 rowgroups * 12 (mat,chunk); block = 256
__global__ __launch_bounds__(256) void proj_qkv(const float* __restrict__ x,
        const float* __restrict__ Wq, const float* __restrict__ Wk,
        const float* __restrict__ Wv,
        float* __restrict__ q_ws, float* __restrict__ newk, float* __restrict__ newv)
{
    int bx = blockIdx.x;
    int rg  = bx / 12;
    int rem = bx % 12;
    int mat = rem >> 2, chunk = rem & 3;
    int o = chunk * 256 + threadIdx.x;
    const float* W  = (mat == 0) ? Wq : ((mat == 1) ? Wk : Wv);
    const float* xr = x + (size_t)rg * 4 * D;

    float a0 = 0.f, a1 = 0.f, a2 = 0.f, a3 = 0.f;
    #pragma unroll 16
    for (int d = 0; d < D; ++d) {
        float w = W[(size_t)d * HD + o];       // coalesced 1KB wave loads, L3-shared
        a0 += xr[d] * w;                       // uniform -> scalar loads
        a1 += xr[D + d] * w;
        a2 += xr[2 * D + d] * w;
        a3 += xr[3 * D + d] * w;
    }
    float acc[4] = {a0, a1, a2, a3};
    #pragma unroll
    for (int i = 0; i < 4; ++i) {
        int row = rg * 4 + i;
        int s = row >> 3, b = row & 7;
        if (mat == 0) {
            q_ws[(size_t)row * HD + o] = acc[i];
        } else {
            float* dst = (mat == 1) ? newk : newv;
            dst[(size_t)((LC + s) * B + b) * HD + o] = acc[i];
        }
    }
}

// ---- fused cache-copy + flash attention (R2 structure, V read from global) --
// grid = B*H*NCH (bh*16 + chunk), block = 256 (4 waves; wave sg owns s in [4sg,4sg+4))
__global__ __launch_bounds__(256) void attn_fused(const float* __restrict__ q_ws,
        const float* __restrict__ cache_k, const float* __restrict__ cache_v,
        float* __restrict__ newk, float* __restrict__ newv,
        float* __restrict__ m_part, float* __restrict__ l_part,
        float* __restrict__ pv_part)
{
    __shared__ float Ks[ST][KPAD];
    __shared__ float qs[S][KPAD];
    __shared__ float sc[S][ST];

    int chunk = blockIdx.x & 15;
    int bh    = blockIdx.x >> 4;
    int h = bh & 15, b = bh >> 4;
    int tid = threadIdx.x, lane = tid & 63, sg = tid >> 6;
    int r = tid >> 4, c = tid & 15;

    // q tile (16x64) into LDS (covered by first barrier)
    *(float4*)&qs[r][c * 4] =
        *(const float4*)(q_ws + ((size_t)(r * B + b)) * HD + h * DH + c * 4);

    float m_prev[4], l_acc[4], pv_acc[4];
    #pragma unroll
    for (int j = 0; j < 4; ++j) { m_prev[j] = -1e30f; l_acc[j] = 0.f; pv_acc[j] = 0.f; }

    // scores + online softmax + PV; V rows read directly from global (L1/L2-hot)
    auto compute_tile = [&](int t0, int nrows, const float* __restrict__ vsrc) {
        float a0 = 0.f, a1 = 0.f, a2 = 0.f, a3 = 0.f;
        #pragma unroll
        for (int i = 0; i < 16; ++i) {
            float4 k4 = *(float4*)&Ks[lane][i * 4];
            float4 q0 = *(float4*)&qs[sg * 4 + 0][i * 4];
            float4 q1 = *(float4*)&qs[sg * 4 + 1][i * 4];
            float4 q2 = *(float4*)&qs[sg * 4 + 2][i * 4];
            float4 q3 = *(float4*)&qs[sg * 4 + 3][i * 4];
            a0 += k4.x * q0.x + k4.y * q0.y + k4.z * q0.z + k4.w * q0.w;
            a1 += k4.x * q1.x + k4.y * q1.y + k4.z * q1.z + k4.w * q1.w;
            a2 += k4.x * q2.x + k4.y * q2.y + k4.z * q2.z + k4.w * q2.w;
            a3 += k4.x * q3.x + k4.y * q3.y + k4.z * q3.z + k4.w * q3.w;
        }
        float a[4] = { a0 * 0.125f, a1 * 0.125f, a2 * 0.125f, a3 * 0.125f };

        int tg = t0 + lane;
        #pragma unroll
        for (int j = 0; j < 4; ++j) {
            int s = sg * 4 + j;
            if (lane >= nrows || tg > LC + s) a[j] = -1e30f;
        }

        float scale_f[4];
        #pragma unroll
        for (int j = 0; j < 4; ++j) {
            float v = a[j];
            #pragma unroll
            for (int msk = 32; msk; msk >>= 1) v = fmaxf(v, __shfl_xor(v, msk));
            float mn = fmaxf(m_prev[j], v);
            scale_f[j] = __expf(m_prev[j] - mn);
            m_prev[j] = mn;
            sc[sg * 4 + j][lane] = __expf(a[j] - mn);
        }
        // own-wave sc writes -> own-wave sc reads: fence + pin scheduler
        asm volatile("s_waitcnt lgkmcnt(0)" ::: "memory");
        __builtin_amdgcn_sched_barrier(0);

        #pragma unroll
        for (int j = 0; j < 4; ++j) { l_acc[j] *= scale_f[j]; pv_acc[j] *= scale_f[j]; }
        #pragma unroll 4
        for (int tt = 0; tt < nrows / 4; ++tt) {
            float v0 = vsrc[(size_t)(tt * 4 + 0) * (B * HD) + lane];
            float v1 = vsrc[(size_t)(tt * 4 + 1) * (B * HD) + lane];
            float v2 = vsrc[(size_t)(tt * 4 + 2) * (B * HD) + lane];
            float v3 = vsrc[(size_t)(tt * 4 + 3) * (B * HD) + lane];
            #pragma unroll
            for (int j = 0; j < 4; ++j) {
                float4 p = *(float4*)&sc[sg * 4 + j][tt * 4];
                pv_acc[j] += p.x * v0 + p.y * v1 + p.z * v2 + p.w * v3;
                l_acc[j]  += p.x + p.y + p.z + p.w;
            }
        }
    };

    int t0base = chunk * CHT;

    for (int it = 0; it < CHT / ST; ++it) {
        int t0 = t0base + it * ST;
        __syncthreads();   // prev tile's LDS readers done
        #pragma unroll
        for (int g = 0; g < 4; ++g) {
            size_t off = ((size_t)(t0 + r + 16 * g) * B + b) * HD + h * DH + c * 4;
            float4 k4 = *(const float4*)(cache_k + off);
            float4 v4 = *(const float4*)(cache_v + off);
            *(float4*)&Ks[r + 16 * g][c * 4] = k4;
            *(float4*)(newk + off) = k4;       // the cache copy
            *(float4*)(newv + off) = v4;
        }
        __syncthreads();   // staged K visible
        compute_tile(t0, ST, cache_v + ((size_t)t0 * B + b) * HD + h * DH);
    }

    if (chunk == NCH - 1) {   // tail: 16 new rows, already in newk/newv from proj_qkv
        __syncthreads();
        {
            size_t off = ((size_t)(LC + r) * B + b) * HD + h * DH + c * 4;
            *(float4*)&Ks[r][c * 4] = *(const float4*)(newk + off);
        }
        __syncthreads();
        compute_tile(LC, S, newv + ((size_t)LC * B + b) * HD + h * DH);
    }

    // emit partials
    int pi = blockIdx.x;
    #pragma unroll
    for (int j = 0; j < 4; ++j) {
        int s = sg * 4 + j;
        pv_part[((size_t)pi * S + s) * DH + lane] = pv_acc[j];
        if (lane == 0) {
            m_part[pi * S + s] = m_prev[j];
            l_part[pi * S + s] = l_acc[j];
        }
    }
}

// ---- combine partials over chunks -> ctx ----------------------------------
__global__ __launch_bounds__(64) void combine(const float* __restrict__ m_part,
        const float* __restrict__ l_part, const float* __restrict__ pv_part,
        float* __restrict__ ctx)
{
    int s  = blockIdx.x & 15;
    int bh = blockIdx.x >> 4;
    int h = bh & 15, b = bh >> 4;
    int d = threadIdx.x;

    float M = -1e30f;
    #pragma unroll
    for (int cc = 0; cc < NCH; ++cc) M = fmaxf(M, m_part[(bh * NCH + cc) * S + s]);
    float L = 0.f, acc = 0.f;
    #pragma unroll
    for (int cc = 0; cc < NCH; ++cc) {
        int pi = bh * NCH + cc;
        float w = __expf(m_part[pi * S + s] - M);
        L   += l_part[pi * S + s] * w;
        acc += w * pv_part[((size_t)pi * S + s) * DH + d];
    }
    ctx[((size_t)(s * B + b)) * HD + h * DH + d] = acc / L;
}

// ---- output projection: 4 rows/block ---------------------------------------
// grid = 32 rowgroups * 4 chunks; block = 256
__global__ __launch_bounds__(256) void proj_o(const float* __restrict__ ctx,
                                              const float* __restrict__ Wo,
                                              float* __restrict__ res)
{
    int bx = blockIdx.x;
    int rg = bx >> 2, chunk = bx & 3;
    int o = chunk * 256 + threadIdx.x;
    const float* cr = ctx + (size_t)rg * 4 * HD;

    float a0 = 0.f, a1 = 0.f, a2 = 0.f, a3 = 0.f;
    #pragma unroll 16
    for (int d = 0; d < HD; ++d) {
        float w = Wo[(size_t)d * D + o];
        a0 += cr[d] * w;
        a1 += cr[HD + d] * w;
        a2 += cr[2 * HD + d] * w;
        a3 += cr[3 * HD + d] * w;
    }
    res[(size_t)(rg * 4 + 0) * D + o] = a0;
    res[(size_t)(rg * 4 + 1) * D + o] = a1;
    res[(size_t)(rg * 4 + 2) * D + o] = a2;
    res[(size_t)(rg * 4 + 3) * D + o] = a3;
}

extern "C" void kernel_launch(void* const* d_in, const int* in_sizes, int n_in,
                              void* d_out, int out_size, void* d_ws, size_t ws_size,
                              hipStream_t stream)
{
    const float* x  = (const float*)d_in[0];
    const float* ck = (const float*)d_in[1];
    const float* cv = (const float*)d_in[2];
    const float* Wq = (const float*)d_in[3];
    const float* Wk = (const float*)d_in[4];
    const float* Wv = (const float*)d_in[5];
    const float* Wo = (const float*)d_in[6];

    float* out  = (float*)d_out;
    float* res  = out;                                   // (S,B,D)
    float* newk = out + (size_t)S * B * D;               // (L,B,H,DH)
    float* newv = newk + (size_t)LMAX * B * H * DH;

    float* q_ws    = (float*)d_ws;                            // S*B*HD
    float* ctx     = q_ws + (size_t)S * B * HD;
    float* m_part  = ctx + (size_t)S * B * HD;
    float* l_part  = m_part + (size_t)B * H * NCH * S;
    float* pv_part = l_part + (size_t)B * H * NCH * S;

    hipLaunchKernelGGL(proj_qkv, dim3(32 * 12), dim3(256), 0, stream,
                       x, Wq, Wk, Wv, q_ws, newk, newv);
    hipLaunchKernelGGL(attn_fused, dim3(B * H * NCH), dim3(256), 0, stream,
                       q_ws, ck, cv, newk, newv, m_part, l_part, pv_part);
    hipLaunchKernelGGL(combine, dim3(B * H * S), dim3(64), 0, stream,
                       m_part, l_part, pv_part, ctx);
    hipLaunchKernelGGL(proj_o, dim3(32 * 4), dim3(256), 0, stream,
                       ctx, Wo, res);
}

// Round 6
// 392.061 us; speedup vs baseline: 1.6232x; 1.1950x over previous
//
#include <hip/hip_runtime.h>
#include <hip/hip_bf16.h>

#define S 16
#define B 8
#define H 16
#define DH 64
#define D 1024
#define HD 1024          // H*DH
#define LC 8192
#define LMAX (LC + S)    // 8208
#define NCH 8            // L-chunks per (b,h)
#define CHT 1024         // t rows per chunk
#define TILE 128         // rows staged per iteration
#define NT (CHT / TILE)  // 8

typedef __attribute__((ext_vector_type(4))) float f4;
typedef __attribute__((ext_vector_type(4))) short s4v;
typedef __attribute__((ext_vector_type(8))) short s8v;

__device__ inline short bfs(float f) {
    __hip_bfloat16 h = __float2bfloat16(f);   // RNE; compiler fuses pairs to cvt_pk
    return __builtin_bit_cast(short, h);
}
__device__ inline s4v pack4(float a, float b, float c, float d) {
    s4v r; r[0] = bfs(a); r[1] = bfs(b); r[2] = bfs(c); r[3] = bfs(d); return r;
}

// ---- QKV projection (R5, proven): 4 rows/block, scalar-uniform x ----------
__global__ __launch_bounds__(256) void proj_qkv(const float* __restrict__ x,
        const float* __restrict__ Wq, const float* __restrict__ Wk,
        const float* __restrict__ Wv,
        float* __restrict__ q_ws, float* __restrict__ newk, float* __restrict__ newv)
{
    int bx = blockIdx.x;
    int rg  = bx / 12;
    int rem = bx % 12;
    int mat = rem >> 2, chunk = rem & 3;
    int o = chunk * 256 + threadIdx.x;
    const float* W  = (mat == 0) ? Wq : ((mat == 1) ? Wk : Wv);
    const float* xr = x + (size_t)rg * 4 * D;

    float a0 = 0.f, a1 = 0.f, a2 = 0.f, a3 = 0.f;
    #pragma unroll 16
    for (int d = 0; d < D; ++d) {
        float w = W[(size_t)d * HD + o];
        a0 += xr[d] * w;
        a1 += xr[D + d] * w;
        a2 += xr[2 * D + d] * w;
        a3 += xr[3 * D + d] * w;
    }
    float acc[4] = {a0, a1, a2, a3};
    #pragma unroll
    for (int i = 0; i < 4; ++i) {
        int row = rg * 4 + i;
        int s = row >> 3, b = row & 7;
        if (mat == 0) {
            q_ws[(size_t)row * HD + o] = acc[i];
        } else {
            float* dst = (mat == 1) ? newk : newv;
            dst[(size_t)((LC + s) * B + b) * HD + o] = acc[i];
        }
    }
}

// ---- fused cache-copy + MFMA flash attention ------------------------------
// grid = B*H*NCH (bh*8 + chunk), block = 256 (4 waves; wave owns 32 t rows/tile)
// D[t][s] = K-frag x Q-frag (16x16x32); its regs ARE the PV B-frag (16x16x16_1k).
__global__ __launch_bounds__(256) void attn_fused(const float* __restrict__ q_ws,
        const float* __restrict__ cache_k, const float* __restrict__ cache_v,
        float* __restrict__ newk, float* __restrict__ newv,
        float* __restrict__ m_part, float* __restrict__ l_part,
        float* __restrict__ pv_part)
{
    extern __shared__ char smem[];
    short* Ksp = (short*)smem;            // [128][64] bf16, XOR-swizzled rows (16KB)
    short* V2p = Ksp + TILE * 64;         // [4 dd][2056] subtiled V (16.45KB)
    float* cpv = (float*)smem;            // phase-disjoint overlay for block merge
    float* cmv = cpv + 4 * 64 * 16;
    float* clv = cmv + 64;

    int chunk = blockIdx.x & (NCH - 1);
    int bh    = blockIdx.x >> 3;
    int h = bh & 15, b = bh >> 4;
    int tid = threadIdx.x, l = tid & 63, wid = tid >> 6;
    int g = l >> 4, c16 = l & 15;
    int rr0 = tid >> 4, cc = tid & 15;
    unsigned v2base = (unsigned)(uintptr_t)V2p;   // LDS byte offset (low 32 bits)

    // Q fragments: lane holds Q[s=c16][k = g*8 + j], scaled by 1/8; 2 k-slices
    s8v qf[2];
    {
        const float* qp = q_ws + ((size_t)(c16 * B + b)) * HD + h * DH + g * 8;
        #pragma unroll
        for (int sl = 0; sl < 2; ++sl) {
            float4 qa = *(const float4*)(qp + sl * 32);
            float4 qb = *(const float4*)(qp + sl * 32 + 4);
            s8v q;
            q[0] = bfs(qa.x * 0.125f); q[1] = bfs(qa.y * 0.125f);
            q[2] = bfs(qa.z * 0.125f); q[3] = bfs(qa.w * 0.125f);
            q[4] = bfs(qb.x * 0.125f); q[5] = bfs(qb.y * 0.125f);
            q[6] = bfs(qb.z * 0.125f); q[7] = bfs(qb.w * 0.125f);
            qf[sl] = q;
        }
    }

    float m_prev = -1e30f, l_acc = 0.f;
    f4 acc[4] = {{0,0,0,0},{0,0,0,0},{0,0,0,0},{0,0,0,0}};

    int t0base = chunk * CHT;

    for (int it = 0; it < NT; ++it) {
        int t0 = t0base + it * TILE;
        __syncthreads();                  // previous tile's LDS readers done
        // ---- stage 128 rows: fp32 copy out, bf16 into LDS (K swizzled, V subtiled)
        #pragma unroll 4
        for (int gg = 0; gg < 8; ++gg) {
            int rr = rr0 + 16 * gg;
            size_t off = ((size_t)(t0 + rr) * B + b) * HD + h * DH + cc * 4;
            float4 k4 = *(const float4*)(cache_k + off);
            float4 v4 = *(const float4*)(cache_v + off);
            *(float4*)(newk + off) = k4;
            *(float4*)(newv + off) = v4;
            int kidx = rr * 64 + ((cc * 4) ^ ((rr & 7) << 3));
            *(s4v*)(Ksp + kidx) = pack4(k4.x, k4.y, k4.z, k4.w);
            int vidx = (cc >> 2) * 2056 + (rr >> 2) * 64 + (rr & 3) * 16 + (cc & 3) * 4;
            *(s4v*)(V2p + vidx) = pack4(v4.x, v4.y, v4.z, v4.w);
        }
        __syncthreads();

        // ---- QK^T: D_h[t][s], t-halves h=0,1 within wave's 32-t window
        f4 d0 = {0,0,0,0}, d1 = {0,0,0,0};
        {
            int row0 = wid * 32 + c16;
            int sw = (row0 & 7) << 3;     // same for row0 and row0+16
            #pragma unroll
            for (int sl = 0; sl < 2; ++sl) {
                int col = (sl * 32 + g * 8) ^ sw;
                s8v k0 = *(const s8v*)(Ksp + row0 * 64 + col);
                s8v k1 = *(const s8v*)(Ksp + (row0 + 16) * 64 + col);
                d0 = __builtin_amdgcn_mfma_f32_16x16x32_bf16(k0, qf[sl], d0, 0, 0, 0);
                d1 = __builtin_amdgcn_mfma_f32_16x16x32_bf16(k1, qf[sl], d1, 0, 0, 0);
            }
        }
        // ---- online softmax (per-lane state for s = c16)
        float hm = fmaxf(fmaxf(fmaxf(d0[0], d0[1]), fmaxf(d0[2], d0[3])),
                         fmaxf(fmaxf(d1[0], d1[1]), fmaxf(d1[2], d1[3])));
        hm = fmaxf(hm, __shfl_xor(hm, 16));
        hm = fmaxf(hm, __shfl_xor(hm, 32));
        float mn = fmaxf(m_prev, hm);
        float sf = __expf(m_prev - mn);
        m_prev = mn;
        f4 p0, p1;
        #pragma unroll
        for (int r = 0; r < 4; ++r) { p0[r] = __expf(d0[r] - mn); p1[r] = __expf(d1[r] - mn); }
        float rs = (p0[0] + p0[1] + p0[2] + p0[3]) + (p1[0] + p1[1] + p1[2] + p1[3]);
        rs += __shfl_xor(rs, 16);
        rs += __shfl_xor(rs, 32);
        l_acc = l_acc * sf + rs;
        #pragma unroll
        for (int dd = 0; dd < 4; ++dd) acc[dd] *= sf;

        // ---- PV: A = V^T via tr-reads, B = P (the D_h regs, cvt to bf16)
        s4v pb0 = pack4(p0[0], p0[1], p0[2], p0[3]);
        s4v pb1 = pack4(p1[0], p1[1], p1[2], p1[3]);
        s4v vfr[4][2];
        #pragma unroll
        for (int dd = 0; dd < 4; ++dd) {
            #pragma unroll
            for (int hh = 0; hh < 2; ++hh) {
                unsigned adr = v2base +
                    2u * (unsigned)(dd * 2056 + (wid * 8 + hh * 4 + g) * 64 + c16);
                asm volatile("ds_read_b64_tr_b16 %0, %1" : "=v"(vfr[dd][hh]) : "v"(adr));
            }
        }
        asm volatile("s_waitcnt lgkmcnt(0)" ::: "memory");
        __builtin_amdgcn_sched_barrier(0);
        #pragma unroll
        for (int dd = 0; dd < 4; ++dd) {
            acc[dd] = __builtin_amdgcn_mfma_f32_16x16x16bf16_1k(vfr[dd][0], pb0, acc[dd], 0, 0, 0);
            acc[dd] = __builtin_amdgcn_mfma_f32_16x16x16bf16_1k(vfr[dd][1], pb1, acc[dd], 0, 0, 0);
        }
    }

    // ---- tail: 16 new rows (t = LC..LC+15), wave 0 only, causal-masked
    if (chunk == NCH - 1) {
        __syncthreads();
        if (rr0 < S) {
            int rr = rr0;
            size_t off = ((size_t)(LC + rr) * B + b) * HD + h * DH + cc * 4;
            float4 k4 = *(const float4*)(newk + off);
            float4 v4 = *(const float4*)(newv + off);
            int kidx = rr * 64 + ((cc * 4) ^ ((rr & 7) << 3));
            *(s4v*)(Ksp + kidx) = pack4(k4.x, k4.y, k4.z, k4.w);
            int vidx = (cc >> 2) * 2056 + (rr >> 2) * 64 + (rr & 3) * 16 + (cc & 3) * 4;
            *(s4v*)(V2p + vidx) = pack4(v4.x, v4.y, v4.z, v4.w);
        }
        __syncthreads();
        if (wid == 0) {
            f4 d0 = {0,0,0,0};
            int sw = (c16 & 7) << 3;
            #pragma unroll
            for (int sl = 0; sl < 2; ++sl) {
                int col = (sl * 32 + g * 8) ^ sw;
                s8v k0 = *(const s8v*)(Ksp + c16 * 64 + col);
                d0 = __builtin_amdgcn_mfma_f32_16x16x32_bf16(k0, qf[sl], d0, 0, 0, 0);
            }
            #pragma unroll
            for (int r = 0; r < 4; ++r)
                if (4 * g + r > c16) d0[r] = -1e30f;     // causal: t > s
            float hm = fmaxf(fmaxf(d0[0], d0[1]), fmaxf(d0[2], d0[3]));
            hm = fmaxf(hm, __shfl_xor(hm, 16));
            hm = fmaxf(hm, __shfl_xor(hm, 32));
            float mn = fmaxf(m_prev, hm);
            float sf = __expf(m_prev - mn);
            m_prev = mn;
            f4 p0;
            #pragma unroll
            for (int r = 0; r < 4; ++r) p0[r] = __expf(d0[r] - mn);
            float rs = p0[0] + p0[1] + p0[2] + p0[3];
            rs += __shfl_xor(rs, 16);
            rs += __shfl_xor(rs, 32);
            l_acc = l_acc * sf + rs;
            #pragma unroll
            for (int dd = 0; dd < 4; ++dd) acc[dd] *= sf;
            s4v pb0 = pack4(p0[0], p0[1], p0[2], p0[3]);
            s4v vfr[4];
            #pragma unroll
            for (int dd = 0; dd < 4; ++dd) {
                unsigned adr = v2base + 2u * (unsigned)(dd * 2056 + g * 64 + c16);
                asm volatile("ds_read_b64_tr_b16 %0, %1" : "=v"(vfr[dd]) : "v"(adr));
            }
            asm volatile("s_waitcnt lgkmcnt(0)" ::: "memory");
            __builtin_amdgcn_sched_barrier(0);
            #pragma unroll
            for (int dd = 0; dd < 4; ++dd)
                acc[dd] = __builtin_amdgcn_mfma_f32_16x16x16bf16_1k(vfr[dd], pb0, acc[dd], 0, 0, 0);
        }
    }

    // ---- intra-block merge of the 4 waves' partials (LDS overlay) --------
    __syncthreads();                       // done with Ksp/V2p
    if (l < 16) { cmv[wid * 16 + l] = m_prev; clv[wid * 16 + l] = l_acc; }
    #pragma unroll
    for (int dd = 0; dd < 4; ++dd)
        #pragma unroll
        for (int r = 0; r < 4; ++r)
            cpv[wid * 1024 + (dd * 16 + g * 4 + r) * 16 + c16] = acc[dd][r];
    __syncthreads();
    int bpi = blockIdx.x;
    if (tid < 16) {
        int s = tid;
        float M = cmv[s];
        #pragma unroll
        for (int w = 1; w < 4; ++w) M = fmaxf(M, cmv[w * 16 + s]);
        float L = 0.f;
        #pragma unroll
        for (int w = 0; w < 4; ++w) {
            float e = __expf(cmv[w * 16 + s] - M);
            L += e * clv[w * 16 + s];
            cmv[w * 16 + s] = e;           // overwrite with weight (own column)
        }
        m_part[bpi * 16 + s] = M;
        l_part[bpi * 16 + s] = L;
    }
    __syncthreads();
    #pragma unroll
    for (int k = 0; k < 4; ++k) {
        int idx = tid + k * 256;
        int d = idx >> 4, s = idx & 15;
        float v = 0.f;
        #pragma unroll
        for (int w = 0; w < 4; ++w) v += cmv[w * 16 + s] * cpv[w * 1024 + d * 16 + s];
        pv_part[((size_t)bpi * 64 + d) * 16 + s] = v;
    }
}

// ---- combine 8 chunk-partials -> ctx --------------------------------------
// grid = B*H (bh), block = 256
__global__ __launch_bounds__(256) void combine(const float* __restrict__ m_part,
        const float* __restrict__ l_part, const float* __restrict__ pv_part,
        float* __restrict__ ctx)
{
    __shared__ float wexp[NCH][16];
    __shared__ float Ls[16];
    int bh = blockIdx.x;
    int h = bh & 15, b = bh >> 4;
    int tid = threadIdx.x;
    if (tid < 16) {
        int s = tid;
        float M = -1e30f;
        #pragma unroll
        for (int c = 0; c < NCH; ++c) M = fmaxf(M, m_part[(bh * NCH + c) * 16 + s]);
        float L = 0.f;
        #pragma unroll
        for (int c = 0; c < NCH; ++c) {
            float e = __expf(m_part[(bh * NCH + c) * 16 + s] - M);
            wexp[c][s] = e;
            L += e * l_part[(bh * NCH + c) * 16 + s];
        }
        Ls[s] = L;
    }
    __syncthreads();
    #pragma unroll
    for (int k = 0; k < 4; ++k) {
        int idx = tid + k * 256;
        int d = idx >> 4, s = idx & 15;
        float v = 0.f;
        #pragma unroll
        for (int c = 0; c < NCH; ++c)
            v += wexp[c][s] * pv_part[((size_t)(bh * NCH + c) * 64 + d) * 16 + s];
        ctx[((size_t)(s * B + b)) * HD + h * DH + d] = v / Ls[s];
    }
}

// ---- output projection (R5, proven): 4 rows/block -------------------------
__global__ __launch_bounds__(256) void proj_o(const float* __restrict__ ctx,
                                              const float* __restrict__ Wo,
                                              float* __restrict__ res)
{
    int bx = blockIdx.x;
    int rg = bx >> 2, chunk = bx & 3;
    int o = chunk * 256 + threadIdx.x;
    const float* cr = ctx + (size_t)rg * 4 * HD;

    float a0 = 0.f, a1 = 0.f, a2 = 0.f, a3 = 0.f;
    #pragma unroll 16
    for (int d = 0; d < HD; ++d) {
        float w = Wo[(size_t)d * D + o];
        a0 += cr[d] * w;
        a1 += cr[HD + d] * w;
        a2 += cr[2 * HD + d] * w;
        a3 += cr[3 * HD + d] * w;
    }
    res[(size_t)(rg * 4 + 0) * D + o] = a0;
    res[(size_t)(rg * 4 + 1) * D + o] = a1;
    res[(size_t)(rg * 4 + 2) * D + o] = a2;
    res[(size_t)(rg * 4 + 3) * D + o] = a3;
}

extern "C" void kernel_launch(void* const* d_in, const int* in_sizes, int n_in,
                              void* d_out, int out_size, void* d_ws, size_t ws_size,
                              hipStream_t stream)
{
    const float* x  = (const float*)d_in[0];
    const float* ck = (const float*)d_in[1];
    const float* cv = (const float*)d_in[2];
    const float* Wq = (const float*)d_in[3];
    const float* Wk = (const float*)d_in[4];
    const float* Wv = (const float*)d_in[5];
    const float* Wo = (const float*)d_in[6];

    float* out  = (float*)d_out;
    float* res  = out;                                   // (S,B,D)
    float* newk = out + (size_t)S * B * D;               // (L,B,H,DH)
    float* newv = newk + (size_t)LMAX * B * H * DH;

    float* q_ws    = (float*)d_ws;                               // 131072 f
    float* ctx     = q_ws + (size_t)S * B * HD;                  // 131072 f
    float* m_part  = ctx + (size_t)S * B * HD;                   // 1024*16 f
    float* l_part  = m_part + (size_t)B * H * NCH * S;           // 1024*16 f
    float* pv_part = l_part + (size_t)B * H * NCH * S;           // 1024*1024 f

    size_t smem = (size_t)TILE * 64 * 2 + 4 * 2056 * 2;          // 32832 B

    hipLaunchKernelGGL(proj_qkv, dim3(32 * 12), dim3(256), 0, stream,
                       x, Wq, Wk, Wv, q_ws, newk, newv);
    hipLaunchKernelGGL(attn_fused, dim3(B * H * NCH), dim3(256), smem, stream,
                       q_ws, ck, cv, newk, newv, m_part, l_part, pv_part);
    hipLaunchKernelGGL(combine, dim3(B * H), dim3(256), 0, stream,
                       m_part, l_part, pv_part, ctx);
    hipLaunchKernelGGL(proj_o, dim3(32 * 4), dim3(256), 0, stream,
                       ctx, Wo, res);
}

// Round 7
// 379.536 us; speedup vs baseline: 1.6768x; 1.0330x over previous
//
#include <hip/hip_runtime.h>
#include <hip/hip_bf16.h>

#define S 16
#define B 8
#define H 16
#define DH 64
#define D 1024
#define HD 1024          // H*DH
#define LC 8192
#define LMAX (LC + S)    // 8208
#define NCH 16           // L-chunks per (b,h)
#define CHT 512          // t rows per chunk
#define TILE 64          // rows staged per iteration
#define NT (CHT / TILE)  // 8

typedef __attribute__((ext_vector_type(4))) float f4;
typedef __attribute__((ext_vector_type(4))) short s4v;
typedef __attribute__((ext_vector_type(8))) short s8v;

__device__ inline short bfs(float f) {
    __hip_bfloat16 h = __float2bfloat16(f);   // RNE; compiler fuses pairs to cvt_pk
    return __builtin_bit_cast(short, h);
}
__device__ inline s4v pack4(float a, float b, float c, float d) {
    s4v r; r[0] = bfs(a); r[1] = bfs(b); r[2] = bfs(c); r[3] = bfs(d); return r;
}

// ---- QKV projection (R5, proven): 4 rows/block, scalar-uniform x ----------
__global__ __launch_bounds__(256) void proj_qkv(const float* __restrict__ x,
        const float* __restrict__ Wq, const float* __restrict__ Wk,
        const float* __restrict__ Wv,
        float* __restrict__ q_ws, float* __restrict__ newk, float* __restrict__ newv)
{
    int bx = blockIdx.x;
    int rg  = bx / 12;
    int rem = bx % 12;
    int mat = rem >> 2, chunk = rem & 3;
    int o = chunk * 256 + threadIdx.x;
    const float* W  = (mat == 0) ? Wq : ((mat == 1) ? Wk : Wv);
    const float* xr = x + (size_t)rg * 4 * D;

    float a0 = 0.f, a1 = 0.f, a2 = 0.f, a3 = 0.f;
    #pragma unroll 16
    for (int d = 0; d < D; ++d) {
        float w = W[(size_t)d * HD + o];
        a0 += xr[d] * w;
        a1 += xr[D + d] * w;
        a2 += xr[2 * D + d] * w;
        a3 += xr[3 * D + d] * w;
    }
    float acc[4] = {a0, a1, a2, a3};
    #pragma unroll
    for (int i = 0; i < 4; ++i) {
        int row = rg * 4 + i;
        int s = row >> 3, b = row & 7;
        if (mat == 0) {
            q_ws[(size_t)row * HD + o] = acc[i];
        } else {
            float* dst = (mat == 1) ? newk : newv;
            dst[(size_t)((LC + s) * B + b) * HD + o] = acc[i];
        }
    }
}

// ---- fused cache-copy + MFMA flash attention ------------------------------
// grid = B*H*NCH (bh*16 + chunk), block = 256 (4 waves; wave owns 16 t rows/tile)
// D[t][s] = K-frag x Q-frag (16x16x32); its regs ARE the PV B-frag (16x16x16_1k).
__global__ __launch_bounds__(256) void attn_fused(const float* __restrict__ q_ws,
        const float* __restrict__ cache_k, const float* __restrict__ cache_v,
        float* __restrict__ newk, float* __restrict__ newv,
        float* __restrict__ m_part, float* __restrict__ l_part,
        float* __restrict__ pv_part)
{
    extern __shared__ char smem[];
    short* Ksp = (short*)smem;            // [64][64] bf16, XOR-swizzled rows (8KB)
    short* V2p = Ksp + TILE * 64;         // [4 dd][1032] subtiled V (8.25KB)
    float* cpv = (float*)smem;            // phase-disjoint overlay for block merge
    float* cmv = cpv + 4 * 64 * 16;
    float* clv = cmv + 64;

    int chunk = blockIdx.x & (NCH - 1);
    int bh    = blockIdx.x >> 4;
    int h = bh & 15, b = bh >> 4;
    int tid = threadIdx.x, l = tid & 63, wid = tid >> 6;
    int g = l >> 4, c16 = l & 15;
    int rr0 = tid >> 4, cc = tid & 15;
    unsigned v2base = (unsigned)(uintptr_t)V2p;   // LDS byte offset (low 32 bits)

    // Q fragments: lane holds Q[s=c16][k = g*8 + j], scaled by 1/8; 2 k-slices
    s8v qf[2];
    {
        const float* qp = q_ws + ((size_t)(c16 * B + b)) * HD + h * DH + g * 8;
        #pragma unroll
        for (int sl = 0; sl < 2; ++sl) {
            float4 qa = *(const float4*)(qp + sl * 32);
            float4 qb = *(const float4*)(qp + sl * 32 + 4);
            s8v q;
            q[0] = bfs(qa.x * 0.125f); q[1] = bfs(qa.y * 0.125f);
            q[2] = bfs(qa.z * 0.125f); q[3] = bfs(qa.w * 0.125f);
            q[4] = bfs(qb.x * 0.125f); q[5] = bfs(qb.y * 0.125f);
            q[6] = bfs(qb.z * 0.125f); q[7] = bfs(qb.w * 0.125f);
            qf[sl] = q;
        }
    }

    float m_prev = -1e30f, l_acc = 0.f;
    f4 acc[4] = {{0,0,0,0},{0,0,0,0},{0,0,0,0},{0,0,0,0}};

    int t0base = chunk * CHT;

    for (int it = 0; it < NT; ++it) {
        int t0 = t0base + it * TILE;
        __syncthreads();                  // previous tile's LDS readers done
        // ---- stage 64 rows: fp32 copy out, bf16 into LDS (K swizzled, V subtiled)
        #pragma unroll
        for (int gg = 0; gg < 4; ++gg) {
            int rr = rr0 + 16 * gg;
            size_t off = ((size_t)(t0 + rr) * B + b) * HD + h * DH + cc * 4;
            float4 k4 = *(const float4*)(cache_k + off);
            float4 v4 = *(const float4*)(cache_v + off);
            *(float4*)(newk + off) = k4;
            *(float4*)(newv + off) = v4;
            int kidx = rr * 64 + ((cc * 4) ^ ((rr & 7) << 3));
            *(s4v*)(Ksp + kidx) = pack4(k4.x, k4.y, k4.z, k4.w);
            int vidx = (cc >> 2) * 1032 + (rr >> 2) * 64 + (rr & 3) * 16 + (cc & 3) * 4;
            *(s4v*)(V2p + vidx) = pack4(v4.x, v4.y, v4.z, v4.w);
        }
        __syncthreads();

        // ---- QK^T: D[t][s] for the wave's 16-t group
        f4 d0 = {0,0,0,0};
        {
            int row0 = wid * 16 + c16;
            int sw = (c16 & 7) << 3;
            #pragma unroll
            for (int sl = 0; sl < 2; ++sl) {
                int col = (sl * 32 + g * 8) ^ sw;
                s8v k0 = *(const s8v*)(Ksp + row0 * 64 + col);
                d0 = __builtin_amdgcn_mfma_f32_16x16x32_bf16(k0, qf[sl], d0, 0, 0, 0);
            }
        }
        // ---- online softmax (per-lane state for s = c16)
        float hm = fmaxf(fmaxf(d0[0], d0[1]), fmaxf(d0[2], d0[3]));
        hm = fmaxf(hm, __shfl_xor(hm, 16));
        hm = fmaxf(hm, __shfl_xor(hm, 32));
        float mn = fmaxf(m_prev, hm);
        float sf = __expf(m_prev - mn);
        m_prev = mn;
        f4 p0;
        #pragma unroll
        for (int r = 0; r < 4; ++r) p0[r] = __expf(d0[r] - mn);
        float rs = (p0[0] + p0[1]) + (p0[2] + p0[3]);
        rs += __shfl_xor(rs, 16);
        rs += __shfl_xor(rs, 32);
        l_acc = l_acc * sf + rs;
        #pragma unroll
        for (int dd = 0; dd < 4; ++dd) acc[dd] *= sf;

        // ---- PV: A = V^T via tr-reads, B = P (the D regs, cvt to bf16)
        s4v pb0 = pack4(p0[0], p0[1], p0[2], p0[3]);
        s4v vfr[4];
        #pragma unroll
        for (int dd = 0; dd < 4; ++dd) {
            unsigned adr = v2base + 2u * (unsigned)(dd * 1032 + (wid * 4 + g) * 64 + c16);
            asm volatile("ds_read_b64_tr_b16 %0, %1" : "=v"(vfr[dd]) : "v"(adr));
        }
        asm volatile("s_waitcnt lgkmcnt(0)" ::: "memory");
        __builtin_amdgcn_sched_barrier(0);
        #pragma unroll
        for (int dd = 0; dd < 4; ++dd)
            acc[dd] = __builtin_amdgcn_mfma_f32_16x16x16bf16_1k(vfr[dd], pb0, acc[dd], 0, 0, 0);
    }

    // ---- tail: 16 new rows (t = LC..LC+15), wave 0 only, causal-masked
    if (chunk == NCH - 1) {
        __syncthreads();
        {
            int rr = rr0;
            size_t off = ((size_t)(LC + rr) * B + b) * HD + h * DH + cc * 4;
            float4 k4 = *(const float4*)(newk + off);
            float4 v4 = *(const float4*)(newv + off);
            int kidx = rr * 64 + ((cc * 4) ^ ((rr & 7) << 3));
            *(s4v*)(Ksp + kidx) = pack4(k4.x, k4.y, k4.z, k4.w);
            int vidx = (cc >> 2) * 1032 + (rr >> 2) * 64 + (rr & 3) * 16 + (cc & 3) * 4;
            *(s4v*)(V2p + vidx) = pack4(v4.x, v4.y, v4.z, v4.w);
        }
        __syncthreads();
        if (wid == 0) {
            f4 d0 = {0,0,0,0};
            int sw = (c16 & 7) << 3;
            #pragma unroll
            for (int sl = 0; sl < 2; ++sl) {
                int col = (sl * 32 + g * 8) ^ sw;
                s8v k0 = *(const s8v*)(Ksp + c16 * 64 + col);
                d0 = __builtin_amdgcn_mfma_f32_16x16x32_bf16(k0, qf[sl], d0, 0, 0, 0);
            }
            #pragma unroll
            for (int r = 0; r < 4; ++r)
                if (4 * g + r > c16) d0[r] = -1e30f;     // causal: t > s
            float hm = fmaxf(fmaxf(d0[0], d0[1]), fmaxf(d0[2], d0[3]));
            hm = fmaxf(hm, __shfl_xor(hm, 16));
            hm = fmaxf(hm, __shfl_xor(hm, 32));
            float mn = fmaxf(m_prev, hm);
            float sf = __expf(m_prev - mn);
            m_prev = mn;
            f4 p0;
            #pragma unroll
            for (int r = 0; r < 4; ++r) p0[r] = __expf(d0[r] - mn);
            float rs = (p0[0] + p0[1]) + (p0[2] + p0[3]);
            rs += __shfl_xor(rs, 16);
            rs += __shfl_xor(rs, 32);
            l_acc = l_acc * sf + rs;
            #pragma unroll
            for (int dd = 0; dd < 4; ++dd) acc[dd] *= sf;
            s4v pb0 = pack4(p0[0], p0[1], p0[2], p0[3]);
            s4v vfr[4];
            #pragma unroll
            for (int dd = 0; dd < 4; ++dd) {
                unsigned adr = v2base + 2u * (unsigned)(dd * 1032 + g * 64 + c16);
                asm volatile("ds_read_b64_tr_b16 %0, %1" : "=v"(vfr[dd]) : "v"(adr));
            }
            asm volatile("s_waitcnt lgkmcnt(0)" ::: "memory");
            __builtin_amdgcn_sched_barrier(0);
            #pragma unroll
            for (int dd = 0; dd < 4; ++dd)
                acc[dd] = __builtin_amdgcn_mfma_f32_16x16x16bf16_1k(vfr[dd], pb0, acc[dd], 0, 0, 0);
        }
    }

    // ---- intra-block merge of the 4 waves' partials (LDS overlay) --------
    __syncthreads();                       // done with Ksp/V2p
    if (l < 16) { cmv[wid * 16 + l] = m_prev; clv[wid * 16 + l] = l_acc; }
    #pragma unroll
    for (int dd = 0; dd < 4; ++dd)
        #pragma unroll
        for (int r = 0; r < 4; ++r)
            cpv[wid * 1024 + (dd * 16 + g * 4 + r) * 16 + c16] = acc[dd][r];
    __syncthreads();
    int bpi = blockIdx.x;
    if (tid < 16) {
        int s = tid;
        float M = cmv[s];
        #pragma unroll
        for (int w = 1; w < 4; ++w) M = fmaxf(M, cmv[w * 16 + s]);
        float L = 0.f;
        #pragma unroll
        for (int w = 0; w < 4; ++w) {
            float e = __expf(cmv[w * 16 + s] - M);
            L += e * clv[w * 16 + s];
            cmv[w * 16 + s] = e;           // overwrite with weight (own column)
        }
        m_part[bpi * 16 + s] = M;
        l_part[bpi * 16 + s] = L;
    }
    __syncthreads();
    #pragma unroll
    for (int k = 0; k < 4; ++k) {
        int idx = tid + k * 256;
        int d = idx >> 4, s = idx & 15;
        float v = 0.f;
        #pragma unroll
        for (int w = 0; w < 4; ++w) v += cmv[w * 16 + s] * cpv[w * 1024 + d * 16 + s];
        pv_part[((size_t)bpi * 64 + d) * 16 + s] = v;
    }
}

// ---- combine 16 chunk-partials -> ctx -------------------------------------
// grid = B*H (bh), block = 256
__global__ __launch_bounds__(256) void combine(const float* __restrict__ m_part,
        const float* __restrict__ l_part, const float* __restrict__ pv_part,
        float* __restrict__ ctx)
{
    __shared__ float wexp[NCH][16];
    __shared__ float Ls[16];
    int bh = blockIdx.x;
    int h = bh & 15, b = bh >> 4;
    int tid = threadIdx.x;
    if (tid < 16) {
        int s = tid;
        float M = -1e30f;
        #pragma unroll
        for (int c = 0; c < NCH; ++c) M = fmaxf(M, m_part[(bh * NCH + c) * 16 + s]);
        float L = 0.f;
        #pragma unroll
        for (int c = 0; c < NCH; ++c) {
            float e = __expf(m_part[(bh * NCH + c) * 16 + s] - M);
            wexp[c][s] = e;
            L += e * l_part[(bh * NCH + c) * 16 + s];
        }
        Ls[s] = L;
    }
    __syncthreads();
    #pragma unroll
    for (int k = 0; k < 4; ++k) {
        int idx = tid + k * 256;
        int d = idx >> 4, s = idx & 15;
        float v = 0.f;
        #pragma unroll
        for (int c = 0; c < NCH; ++c)
            v += wexp[c][s] * pv_part[((size_t)(bh * NCH + c) * 64 + d) * 16 + s];
        ctx[((size_t)(s * B + b)) * HD + h * DH + d] = v / Ls[s];
    }
}

// ---- output projection (R5, proven): 4 rows/block -------------------------
__global__ __launch_bounds__(256) void proj_o(const float* __restrict__ ctx,
                                              const float* __restrict__ Wo,
                                              float* __restrict__ res)
{
    int bx = blockIdx.x;
    int rg = bx >> 2, chunk = bx & 3;
    int o = chunk * 256 + threadIdx.x;
    const float* cr = ctx + (size_t)rg * 4 * HD;

    float a0 = 0.f, a1 = 0.f, a2 = 0.f, a3 = 0.f;
    #pragma unroll 16
    for (int d = 0; d < HD; ++d) {
        float w = Wo[(size_t)d * D + o];
        a0 += cr[d] * w;
        a1 += cr[HD + d] * w;
        a2 += cr[2 * HD + d] * w;
        a3 += cr[3 * HD + d] * w;
    }
    res[(size_t)(rg * 4 + 0) * D + o] = a0;
    res[(size_t)(rg * 4 + 1) * D + o] = a1;
    res[(size_t)(rg * 4 + 2) * D + o] = a2;
    res[(size_t)(rg * 4 + 3) * D + o] = a3;
}

extern "C" void kernel_launch(void* const* d_in, const int* in_sizes, int n_in,
                              void* d_out, int out_size, void* d_ws, size_t ws_size,
                              hipStream_t stream)
{
    const float* x  = (const float*)d_in[0];
    const float* ck = (const float*)d_in[1];
    const float* cv = (const float*)d_in[2];
    const float* Wq = (const float*)d_in[3];
    const float* Wk = (const float*)d_in[4];
    const float* Wv = (const float*)d_in[5];
    const float* Wo = (const float*)d_in[6];

    float* out  = (float*)d_out;
    float* res  = out;                                   // (S,B,D)
    float* newk = out + (size_t)S * B * D;               // (L,B,H,DH)
    float* newv = newk + (size_t)LMAX * B * H * DH;

    float* q_ws    = (float*)d_ws;                               // 131072 f
    float* ctx     = q_ws + (size_t)S * B * HD;                  // 131072 f
    float* m_part  = ctx + (size_t)S * B * HD;                   // 2048*16 f
    float* l_part  = m_part + (size_t)B * H * NCH * S;           // 2048*16 f
    float* pv_part = l_part + (size_t)B * H * NCH * S;           // 2048*1024 f

    size_t smem = (size_t)(4 * 64 * 16 + 64 + 64) * 4;           // 16896 B (overlay max)

    hipLaunchKernelGGL(proj_qkv, dim3(32 * 12), dim3(256), 0, stream,
                       x, Wq, Wk, Wv, q_ws, newk, newv);
    hipLaunchKernelGGL(attn_fused, dim3(B * H * NCH), dim3(256), smem, stream,
                       q_ws, ck, cv, newk, newv, m_part, l_part, pv_part);
    hipLaunchKernelGGL(combine, dim3(B * H), dim3(256), 0, stream,
                       m_part, l_part, pv_part, ctx);
    hipLaunchKernelGGL(proj_o, dim3(32 * 4), dim3(256), 0, stream,
                       ctx, Wo, res);
}

// Round 9
// 371.523 us; speedup vs baseline: 1.7130x; 1.0216x over previous
//
#include <hip/hip_runtime.h>
#include <hip/hip_bf16.h>

#define S 16
#define B 8
#define H 16
#define DH 64
#define D 1024
#define HD 1024          // H*DH
#define LC 8192
#define LMAX (LC + S)    // 8208
#define NCH 16           // L-chunks per (b,h)
#define CHT 512          // t rows per chunk
#define TILE 64          // rows staged per iteration
#define NT (CHT / TILE)  // 8

typedef __attribute__((ext_vector_type(4))) float f4;
typedef __attribute__((ext_vector_type(4))) short s4v;
typedef __attribute__((ext_vector_type(8))) short s8v;

__device__ inline short bfs(float f) {
    __hip_bfloat16 h = __float2bfloat16(f);   // RNE; compiler fuses pairs to cvt_pk
    return __builtin_bit_cast(short, h);
}
__device__ inline s4v pack4(float a, float b, float c, float d) {
    s4v r; r[0] = bfs(a); r[1] = bfs(b); r[2] = bfs(c); r[3] = bfs(d); return r;
}

// ---- QKV projection (R5, proven): 4 rows/block, scalar-uniform x ----------
__global__ __launch_bounds__(256) void proj_qkv(const float* __restrict__ x,
        const float* __restrict__ Wq, const float* __restrict__ Wk,
        const float* __restrict__ Wv,
        float* __restrict__ q_ws, float* __restrict__ newk, float* __restrict__ newv)
{
    int bx = blockIdx.x;
    int rg  = bx / 12;
    int rem = bx % 12;
    int mat = rem >> 2, chunk = rem & 3;
    int o = chunk * 256 + threadIdx.x;
    const float* W  = (mat == 0) ? Wq : ((mat == 1) ? Wk : Wv);
    const float* xr = x + (size_t)rg * 4 * D;

    float a0 = 0.f, a1 = 0.f, a2 = 0.f, a3 = 0.f;
    #pragma unroll 16
    for (int d = 0; d < D; ++d) {
        float w = W[(size_t)d * HD + o];
        a0 += xr[d] * w;
        a1 += xr[D + d] * w;
        a2 += xr[2 * D + d] * w;
        a3 += xr[3 * D + d] * w;
    }
    float acc[4] = {a0, a1, a2, a3};
    #pragma unroll
    for (int i = 0; i < 4; ++i) {
        int row = rg * 4 + i;
        int s = row >> 3, b = row & 7;
        if (mat == 0) {
            q_ws[(size_t)row * HD + o] = acc[i];
        } else {
            float* dst = (mat == 1) ? newk : newv;
            dst[(size_t)((LC + s) * B + b) * HD + o] = acc[i];
        }
    }
}

// ---- fused cache-copy + MFMA flash attention ------------------------------
// grid = B*H*NCH (bh*16 + chunk), block = 256 (4 waves; wave owns 16 t rows/tile)
// D[t][s] = K-frag x Q-frag (16x16x32); its regs ARE the PV B-frag (16x16x16_1k).
// Main-loop barriers are lgkm-only: copy-out stores stay in flight (never drained).
__global__ __launch_bounds__(256) void attn_fused(const float* __restrict__ q_ws,
        const float* __restrict__ cache_k, const float* __restrict__ cache_v,
        float* __restrict__ newk, float* __restrict__ newv,
        float* __restrict__ m_part, float* __restrict__ l_part,
        float* __restrict__ pv_part)
{
    extern __shared__ char smem[];
    short* Ksp = (short*)smem;            // [64][64] bf16, XOR-swizzled rows (8KB)
    short* V2p = Ksp + TILE * 64;         // [4 dd][1032] subtiled V (8.25KB)
    float* cpv = (float*)smem;            // phase-disjoint overlay for block merge
    float* cmv = cpv + 4 * 64 * 16;
    float* clv = cmv + 64;

    int chunk = blockIdx.x & (NCH - 1);
    int bh    = blockIdx.x >> 4;
    int h = bh & 15, b = bh >> 4;
    int tid = threadIdx.x, l = tid & 63, wid = tid >> 6;
    int g = l >> 4, c16 = l & 15;
    int rr0 = tid >> 4, cc = tid & 15;
    unsigned v2base = (unsigned)(uintptr_t)V2p;   // LDS byte offset (low 32 bits)

    // Q fragments: lane holds Q[s=c16][k = g*8 + j], scaled by 1/8; 2 k-slices
    s8v qf[2];
    {
        const float* qp = q_ws + ((size_t)(c16 * B + b)) * HD + h * DH + g * 8;
        #pragma unroll
        for (int sl = 0; sl < 2; ++sl) {
            float4 qa = *(const float4*)(qp + sl * 32);
            float4 qb = *(const float4*)(qp + sl * 32 + 4);
            s8v q;
            q[0] = bfs(qa.x * 0.125f); q[1] = bfs(qa.y * 0.125f);
            q[2] = bfs(qa.z * 0.125f); q[3] = bfs(qa.w * 0.125f);
            q[4] = bfs(qb.x * 0.125f); q[5] = bfs(qb.y * 0.125f);
            q[6] = bfs(qb.z * 0.125f); q[7] = bfs(qb.w * 0.125f);
            qf[sl] = q;
        }
    }

    float m_prev = -1e30f, l_acc = 0.f;
    f4 acc[4] = {{0,0,0,0},{0,0,0,0},{0,0,0,0},{0,0,0,0}};

    int t0base = chunk * CHT;

    for (int it = 0; it < NT; ++it) {
        int t0 = t0base + it * TILE;
        // barrier 1: previous tile's LDS readers done (lgkm already drained by
        // each wave before its MFMAs; stores NOT drained)
        asm volatile("s_waitcnt lgkmcnt(0)" ::: "memory");
        __builtin_amdgcn_s_barrier();
        __builtin_amdgcn_sched_barrier(0);

        // ---- stage 64 rows: fp32 copy out (NT), bf16 into LDS (K swz, V subtiled)
        #pragma unroll
        for (int gg = 0; gg < 4; ++gg) {
            int rr = rr0 + 16 * gg;
            size_t off = ((size_t)(t0 + rr) * B + b) * HD + h * DH + cc * 4;
            f4 k4 = __builtin_nontemporal_load((const f4*)(cache_k + off));
            f4 v4 = __builtin_nontemporal_load((const f4*)(cache_v + off));
            __builtin_nontemporal_store(k4, (f4*)(newk + off));
            __builtin_nontemporal_store(v4, (f4*)(newv + off));
            int kidx = rr * 64 + ((cc * 4) ^ ((rr & 7) << 3));
            *(s4v*)(Ksp + kidx) = pack4(k4[0], k4[1], k4[2], k4[3]);
            int vidx = (cc >> 2) * 1032 + (rr >> 2) * 64 + (rr & 3) * 16 + (cc & 3) * 4;
            *(s4v*)(V2p + vidx) = pack4(v4[0], v4[1], v4[2], v4[3]);
        }
        // barrier 2: staging ds_writes visible (lgkm only; stores in flight)
        asm volatile("s_waitcnt lgkmcnt(0)" ::: "memory");
        __builtin_amdgcn_s_barrier();
        __builtin_amdgcn_sched_barrier(0);

        // ---- QK^T: D[t][s] for the wave's 16-t group
        f4 d0 = {0,0,0,0};
        {
            int row0 = wid * 16 + c16;
            int sw = (c16 & 7) << 3;
            #pragma unroll
            for (int sl = 0; sl < 2; ++sl) {
                int col = (sl * 32 + g * 8) ^ sw;
                s8v k0 = *(const s8v*)(Ksp + row0 * 64 + col);
                d0 = __builtin_amdgcn_mfma_f32_16x16x32_bf16(k0, qf[sl], d0, 0, 0, 0);
            }
        }
        // ---- online softmax (per-lane state for s = c16)
        float hm = fmaxf(fmaxf(d0[0], d0[1]), fmaxf(d0[2], d0[3]));
        hm = fmaxf(hm, __shfl_xor(hm, 16));
        hm = fmaxf(hm, __shfl_xor(hm, 32));
        float mn = fmaxf(m_prev, hm);
        float sf = __expf(m_prev - mn);
        m_prev = mn;
        f4 p0;
        #pragma unroll
        for (int r = 0; r < 4; ++r) p0[r] = __expf(d0[r] - mn);
        float rs = (p0[0] + p0[1]) + (p0[2] + p0[3]);
        rs += __shfl_xor(rs, 16);
        rs += __shfl_xor(rs, 32);
        l_acc = l_acc * sf + rs;
        #pragma unroll
        for (int dd = 0; dd < 4; ++dd) acc[dd] *= sf;

        // ---- PV: A = V^T via tr-reads, B = P (the D regs, cvt to bf16)
        s4v pb0 = pack4(p0[0], p0[1], p0[2], p0[3]);
        s4v vfr[4];
        #pragma unroll
        for (int dd = 0; dd < 4; ++dd) {
            unsigned adr = v2base + 2u * (unsigned)(dd * 1032 + (wid * 4 + g) * 64 + c16);
            asm volatile("ds_read_b64_tr_b16 %0, %1" : "=v"(vfr[dd]) : "v"(adr));
        }
        asm volatile("s_waitcnt lgkmcnt(0)" ::: "memory");
        __builtin_amdgcn_sched_barrier(0);
        #pragma unroll
        for (int dd = 0; dd < 4; ++dd)
            acc[dd] = __builtin_amdgcn_mfma_f32_16x16x16bf16_1k(vfr[dd], pb0, acc[dd], 0, 0, 0);
    }

    // ---- tail: 16 new rows (t = LC..LC+15), wave 0 only, causal-masked
    if (chunk == NCH - 1) {
        __syncthreads();
        {
            int rr = rr0;
            size_t off = ((size_t)(LC + rr) * B + b) * HD + h * DH + cc * 4;
            float4 k4 = *(const float4*)(newk + off);
            float4 v4 = *(const float4*)(newv + off);
            int kidx = rr * 64 + ((cc * 4) ^ ((rr & 7) << 3));
            *(s4v*)(Ksp + kidx) = pack4(k4.x, k4.y, k4.z, k4.w);
            int vidx = (cc >> 2) * 1032 + (rr >> 2) * 64 + (rr & 3) * 16 + (cc & 3) * 4;
            *(s4v*)(V2p + vidx) = pack4(v4.x, v4.y, v4.z, v4.w);
        }
        __syncthreads();
        if (wid == 0) {
            f4 d0 = {0,0,0,0};
            int sw = (c16 & 7) << 3;
            #pragma unroll
            for (int sl = 0; sl < 2; ++sl) {
                int col = (sl * 32 + g * 8) ^ sw;
                s8v k0 = *(const s8v*)(Ksp + c16 * 64 + col);
                d0 = __builtin_amdgcn_mfma_f32_16x16x32_bf16(k0, qf[sl], d0, 0, 0, 0);
            }
            #pragma unroll
            for (int r = 0; r < 4; ++r)
                if (4 * g + r > c16) d0[r] = -1e30f;     // causal: t > s
            float hm = fmaxf(fmaxf(d0[0], d0[1]), fmaxf(d0[2], d0[3]));
            hm = fmaxf(hm, __shfl_xor(hm, 16));
            hm = fmaxf(hm, __shfl_xor(hm, 32));
            float mn = fmaxf(m_prev, hm);
            float sf = __expf(m_prev - mn);
            m_prev = mn;
            f4 p0;
            #pragma unroll
            for (int r = 0; r < 4; ++r) p0[r] = __expf(d0[r] - mn);
            float rs = (p0[0] + p0[1]) + (p0[2] + p0[3]);
            rs += __shfl_xor(rs, 16);
            rs += __shfl_xor(rs, 32);
            l_acc = l_acc * sf + rs;
            #pragma unroll
            for (int dd = 0; dd < 4; ++dd) acc[dd] *= sf;
            s4v pb0 = pack4(p0[0], p0[1], p0[2], p0[3]);
            s4v vfr[4];
            #pragma unroll
            for (int dd = 0; dd < 4; ++dd) {
                unsigned adr = v2base + 2u * (unsigned)(dd * 1032 + g * 64 + c16);
                asm volatile("ds_read_b64_tr_b16 %0, %1" : "=v"(vfr[dd]) : "v"(adr));
            }
            asm volatile("s_waitcnt lgkmcnt(0)" ::: "memory");
            __builtin_amdgcn_sched_barrier(0);
            #pragma unroll
            for (int dd = 0; dd < 4; ++dd)
                acc[dd] = __builtin_amdgcn_mfma_f32_16x16x16bf16_1k(vfr[dd], pb0, acc[dd], 0, 0, 0);
        }
    }

    // ---- intra-block merge of the 4 waves' partials (LDS overlay) --------
    __syncthreads();                       // done with Ksp/V2p
    if (l < 16) { cmv[wid * 16 + l] = m_prev; clv[wid * 16 + l] = l_acc; }
    #pragma unroll
    for (int dd = 0; dd < 4; ++dd)
        #pragma unroll
        for (int r = 0; r < 4; ++r)
            cpv[wid * 1024 + (dd * 16 + g * 4 + r) * 16 + c16] = acc[dd][r];
    __syncthreads();
    int bpi = blockIdx.x;
    if (tid < 16) {
        int s = tid;
        float M = cmv[s];
        #pragma unroll
        for (int w = 1; w < 4; ++w) M = fmaxf(M, cmv[w * 16 + s]);
        float L = 0.f;
        #pragma unroll
        for (int w = 0; w < 4; ++w) {
            float e = __expf(cmv[w * 16 + s] - M);
            L += e * clv[w * 16 + s];
            cmv[w * 16 + s] = e;           // overwrite with weight (own column)
        }
        m_part[bpi * 16 + s] = M;
        l_part[bpi * 16 + s] = L;
    }
    __syncthreads();
    #pragma unroll
    for (int k = 0; k < 4; ++k) {
        int idx = tid + k * 256;
        int d = idx >> 4, s = idx & 15;
        float v = 0.f;
        #pragma unroll
        for (int w = 0; w < 4; ++w) v += cmv[w * 16 + s] * cpv[w * 1024 + d * 16 + s];
        pv_part[((size_t)bpi * 64 + d) * 16 + s] = v;
    }
}

// ---- combine 16 chunk-partials -> ctx -------------------------------------
// grid = B*H (bh), block = 256
__global__ __launch_bounds__(256) void combine(const float* __restrict__ m_part,
        const float* __restrict__ l_part, const float* __restrict__ pv_part,
        float* __restrict__ ctx)
{
    __shared__ float wexp[NCH][16];
    __shared__ float Ls[16];
    int bh = blockIdx.x;
    int h = bh & 15, b = bh >> 4;
    int tid = threadIdx.x;
    if (tid < 16) {
        int s = tid;
        float M = -1e30f;
        #pragma unroll
        for (int c = 0; c < NCH; ++c) M = fmaxf(M, m_part[(bh * NCH + c) * 16 + s]);
        float L = 0.f;
        #pragma unroll
        for (int c = 0; c < NCH; ++c) {
            float e = __expf(m_part[(bh * NCH + c) * 16 + s] - M);
            wexp[c][s] = e;
            L += e * l_part[(bh * NCH + c) * 16 + s];
        }
        Ls[s] = L;
    }
    __syncthreads();
    #pragma unroll
    for (int k = 0; k < 4; ++k) {
        int idx = tid + k * 256;
        int d = idx >> 4, s = idx & 15;
        float v = 0.f;
        #pragma unroll
        for (int c = 0; c < NCH; ++c)
            v += wexp[c][s] * pv_part[((size_t)(bh * NCH + c) * 64 + d) * 16 + s];
        ctx[((size_t)(s * B + b)) * HD + h * DH + d] = v / Ls[s];
    }
}

// ---- output projection (R5, proven): 4 rows/block -------------------------
__global__ __launch_bounds__(256) void proj_o(const float* __restrict__ ctx,
                                              const float* __restrict__ Wo,
                                              float* __restrict__ res)
{
    int bx = blockIdx.x;
    int rg = bx >> 2, chunk = bx & 3;
    int o = chunk * 256 + threadIdx.x;
    const float* cr = ctx + (size_t)rg * 4 * HD;

    float a0 = 0.f, a1 = 0.f, a2 = 0.f, a3 = 0.f;
    #pragma unroll 16
    for (int d = 0; d < HD; ++d) {
        float w = Wo[(size_t)d * D + o];
        a0 += cr[d] * w;
        a1 += cr[HD + d] * w;
        a2 += cr[2 * HD + d] * w;
        a3 += cr[3 * HD + d] * w;
    }
    res[(size_t)(rg * 4 + 0) * D + o] = a0;
    res[(size_t)(rg * 4 + 1) * D + o] = a1;
    res[(size_t)(rg * 4 + 2) * D + o] = a2;
    res[(size_t)(rg * 4 + 3) * D + o] = a3;
}

extern "C" void kernel_launch(void* const* d_in, const int* in_sizes, int n_in,
                              void* d_out, int out_size, void* d_ws, size_t ws_size,
                              hipStream_t stream)
{
    const float* x  = (const float*)d_in[0];
    const float* ck = (const float*)d_in[1];
    const float* cv = (const float*)d_in[2];
    const float* Wq = (const float*)d_in[3];
    const float* Wk = (const float*)d_in[4];
    const float* Wv = (const float*)d_in[5];
    const float* Wo = (const float*)d_in[6];

    float* out  = (float*)d_out;
    float* res  = out;                                   // (S,B,D)
    float* newk = out + (size_t)S * B * D;               // (L,B,H,DH)
    float* newv = newk + (size_t)LMAX * B * H * DH;

    float* q_ws    = (float*)d_ws;                               // 131072 f
    float* ctx     = q_ws + (size_t)S * B * HD;                  // 131072 f
    float* m_part  = ctx + (size_t)S * B * HD;                   // 2048*16 f
    float* l_part  = m_part + (size_t)B * H * NCH * S;           // 2048*16 f
    float* pv_part = l_part + (size_t)B * H * NCH * S;           // 2048*1024 f

    size_t smem = (size_t)(4 * 64 * 16 + 64 + 64) * 4;           // 16896 B (overlay max)

    hipLaunchKernelGGL(proj_qkv, dim3(32 * 12), dim3(256), 0, stream,
                       x, Wq, Wk, Wv, q_ws, newk, newv);
    hipLaunchKernelGGL(attn_fused, dim3(B * H * NCH), dim3(256), smem, stream,
                       q_ws, ck, cv, newk, newv, m_part, l_part, pv_part);
    hipLaunchKernelGGL(combine, dim3(B * H), dim3(256), 0, stream,
                       m_part, l_part, pv_part, ctx);
    hipLaunchKernelGGL(proj_o, dim3(32 * 4), dim3(256), 0, stream,
                       ctx, Wo, res);
}

// Round 10
// 358.700 us; speedup vs baseline: 1.7742x; 1.0357x over previous
//
#include <hip/hip_runtime.h>
#include <hip/hip_bf16.h>

#define S 16
#define B 8
#define H 16
#define DH 64
#define D 1024
#define HD 1024          // H*DH
#define LC 8192
#define LMAX (LC + S)    // 8208
#define NCH 32           // L-chunks per (b,hg)
#define CHT 256          // t rows per chunk
#define TILE 32          // rows staged per iteration
#define NT (CHT / TILE)  // 8

typedef __attribute__((ext_vector_type(4))) float f4;
typedef __attribute__((ext_vector_type(4))) short s4v;
typedef __attribute__((ext_vector_type(8))) short s8v;

__device__ inline short bfs(float f) {
    __hip_bfloat16 h = __float2bfloat16(f);   // RNE; pairs fuse to cvt_pk
    return __builtin_bit_cast(short, h);
}
__device__ inline s4v pack4(float a, float b, float c, float d) {
    s4v r; r[0] = bfs(a); r[1] = bfs(b); r[2] = bfs(c); r[3] = bfs(d); return r;
}

// ---- QKV projection (R5, proven): 4 rows/block, scalar-uniform x ----------
__global__ __launch_bounds__(256) void proj_qkv(const float* __restrict__ x,
        const float* __restrict__ Wq, const float* __restrict__ Wk,
        const float* __restrict__ Wv,
        float* __restrict__ q_ws, float* __restrict__ newk, float* __restrict__ newv)
{
    int bx = blockIdx.x;
    int rg  = bx / 12;
    int rem = bx % 12;
    int mat = rem >> 2, chunk = rem & 3;
    int o = chunk * 256 + threadIdx.x;
    const float* W  = (mat == 0) ? Wq : ((mat == 1) ? Wk : Wv);
    const float* xr = x + (size_t)rg * 4 * D;

    float a0 = 0.f, a1 = 0.f, a2 = 0.f, a3 = 0.f;
    #pragma unroll 16
    for (int d = 0; d < D; ++d) {
        float w = W[(size_t)d * HD + o];
        a0 += xr[d] * w;
        a1 += xr[D + d] * w;
        a2 += xr[2 * D + d] * w;
        a3 += xr[3 * D + d] * w;
    }
    float acc[4] = {a0, a1, a2, a3};
    #pragma unroll
    for (int i = 0; i < 4; ++i) {
        int row = rg * 4 + i;
        int s = row >> 3, b = row & 7;
        if (mat == 0) {
            q_ws[(size_t)row * HD + o] = acc[i];
        } else {
            float* dst = (mat == 1) ? newk : newv;
            dst[(size_t)((LC + s) * B + b) * HD + o] = acc[i];
        }
    }
}

// ---- fused cache-copy + MFMA flash attention, head-group blocking ---------
// grid = B*4*NCH: bx -> chunk (0..31), hg (0..3), b (0..7).
// Block stages [TILE=32 t] x [4 heads x 64 dh] = 1KB-contiguous rows (DRAM-friendly).
// Wave w owns head hg*4+w completely: QK^T (D[t][s] = K x Q), softmax, PV.
__global__ __launch_bounds__(256) void attn_fused(const float* __restrict__ q_ws,
        const float* __restrict__ cache_k, const float* __restrict__ cache_v,
        float* __restrict__ newk, float* __restrict__ newv,
        float* __restrict__ m_part, float* __restrict__ l_part,
        float* __restrict__ pv_part)
{
    extern __shared__ char smem[];
    short* Ksp = (short*)smem;            // [32][256] bf16, XOR-swz per 64-elem head slice (16KB)
    short* Vp  = Ksp + TILE * 256;        // 4 heads x (4 dd x 520) subtiled V (16640B)

    int bx = blockIdx.x;
    int chunk = bx & 31;
    int hgb = bx >> 5;
    int hg = hgb & 3, b = hgb >> 2;
    int tid = threadIdx.x, l = tid & 63, wid = tid >> 6;
    int g = l >> 4, c16 = l & 15;
    int h = hg * 4 + wid;                 // this wave's head
    unsigned vbase = (unsigned)(uintptr_t)Vp + (unsigned)wid * 4160u;

    // Q fragments for head h: lane holds Q[s=c16][k=g*8+j], scaled by 1/8
    s8v qf[2];
    {
        const float* qp = q_ws + ((size_t)(c16 * B + b)) * HD + h * DH + g * 8;
        #pragma unroll
        for (int sl = 0; sl < 2; ++sl) {
            float4 qa = *(const float4*)(qp + sl * 32);
            float4 qb = *(const float4*)(qp + sl * 32 + 4);
            s8v q;
            q[0] = bfs(qa.x * 0.125f); q[1] = bfs(qa.y * 0.125f);
            q[2] = bfs(qa.z * 0.125f); q[3] = bfs(qa.w * 0.125f);
            q[4] = bfs(qb.x * 0.125f); q[5] = bfs(qb.y * 0.125f);
            q[6] = bfs(qb.z * 0.125f); q[7] = bfs(qb.w * 0.125f);
            qf[sl] = q;
        }
    }

    float m_prev = -1e30f, l_acc = 0.f;
    f4 acc[4] = {{0,0,0,0},{0,0,0,0},{0,0,0,0},{0,0,0,0}};

    int t0base = chunk * CHT;
    int sw = (c16 & 7) << 3;

    for (int it = 0; it < NT; ++it) {
        int t0 = t0base + it * TILE;
        // barrier 1: previous tile's LDS readers done (stores stay in flight)
        asm volatile("s_waitcnt lgkmcnt(0)" ::: "memory");
        __builtin_amdgcn_s_barrier();
        __builtin_amdgcn_sched_barrier(0);

        // ---- stage 32 rows x 1KB (K,V): copy out fp32, pack bf16 into LDS
        #pragma unroll
        for (int gg = 0; gg < 8; ++gg) {
            int idx = tid + gg * 256;
            int rr = idx >> 6, ch = idx & 63;       // row, 16B-chunk within 1KB row
            size_t off = ((size_t)(t0 + rr)) * 8192 + (size_t)b * 1024 + hg * 256 + ch * 4;
            f4 k4 = __builtin_nontemporal_load((const f4*)(cache_k + off));
            f4 v4 = __builtin_nontemporal_load((const f4*)(cache_v + off));
            __builtin_nontemporal_store(k4, (f4*)(newk + off));
            __builtin_nontemporal_store(v4, (f4*)(newv + off));
            int w = ch >> 4, cc = ch & 15;
            int kidx = rr * 256 + w * 64 + ((cc * 4) ^ ((rr & 7) << 3));
            *(s4v*)(Ksp + kidx) = pack4(k4[0], k4[1], k4[2], k4[3]);
            int vidx = w * 2080 + (cc >> 2) * 520 + (rr >> 2) * 64 + (rr & 3) * 16 + (cc & 3) * 4;
            *(s4v*)(Vp + vidx) = pack4(v4[0], v4[1], v4[2], v4[3]);
        }
        // barrier 2: staging ds_writes visible (lgkm only)
        asm volatile("s_waitcnt lgkmcnt(0)" ::: "memory");
        __builtin_amdgcn_s_barrier();
        __builtin_amdgcn_sched_barrier(0);

        // ---- QK^T: D[t][s], two 16-t groups of this head's 32 rows
        f4 d0 = {0,0,0,0}, d1 = {0,0,0,0};
        #pragma unroll
        for (int sl = 0; sl < 2; ++sl) {
            int col = (sl * 32 + g * 8) ^ sw;
            s8v k0 = *(const s8v*)(Ksp + c16 * 256 + wid * 64 + col);
            s8v k1 = *(const s8v*)(Ksp + (16 + c16) * 256 + wid * 64 + col);
            d0 = __builtin_amdgcn_mfma_f32_16x16x32_bf16(k0, qf[sl], d0, 0, 0, 0);
            d1 = __builtin_amdgcn_mfma_f32_16x16x32_bf16(k1, qf[sl], d1, 0, 0, 0);
        }
        // ---- online softmax (per-lane state for s = c16)
        float hm = fmaxf(fmaxf(fmaxf(d0[0], d0[1]), fmaxf(d0[2], d0[3])),
                         fmaxf(fmaxf(d1[0], d1[1]), fmaxf(d1[2], d1[3])));
        hm = fmaxf(hm, __shfl_xor(hm, 16));
        hm = fmaxf(hm, __shfl_xor(hm, 32));
        float mn = fmaxf(m_prev, hm);
        float sf = __expf(m_prev - mn);
        m_prev = mn;
        f4 p0, p1;
        #pragma unroll
        for (int r = 0; r < 4; ++r) { p0[r] = __expf(d0[r] - mn); p1[r] = __expf(d1[r] - mn); }
        float rs = (p0[0] + p0[1] + p0[2] + p0[3]) + (p1[0] + p1[1] + p1[2] + p1[3]);
        rs += __shfl_xor(rs, 16);
        rs += __shfl_xor(rs, 32);
        l_acc = l_acc * sf + rs;
        #pragma unroll
        for (int dd = 0; dd < 4; ++dd) acc[dd] *= sf;

        // ---- PV: A = V^T via tr-reads (per-head subtiles), B = P
        s4v pb0 = pack4(p0[0], p0[1], p0[2], p0[3]);
        s4v pb1 = pack4(p1[0], p1[1], p1[2], p1[3]);
        s4v vfr[4][2];
        #pragma unroll
        for (int dd = 0; dd < 4; ++dd) {
            #pragma unroll
            for (int hh = 0; hh < 2; ++hh) {
                unsigned adr = vbase + 2u * (unsigned)(dd * 520 + (hh * 4 + g) * 64 + c16);
                asm volatile("ds_read_b64_tr_b16 %0, %1" : "=v"(vfr[dd][hh]) : "v"(adr));
            }
        }
        asm volatile("s_waitcnt lgkmcnt(0)" ::: "memory");
        __builtin_amdgcn_sched_barrier(0);
        #pragma unroll
        for (int dd = 0; dd < 4; ++dd) {
            acc[dd] = __builtin_amdgcn_mfma_f32_16x16x16bf16_1k(vfr[dd][0], pb0, acc[dd], 0, 0, 0);
            acc[dd] = __builtin_amdgcn_mfma_f32_16x16x16bf16_1k(vfr[dd][1], pb1, acc[dd], 0, 0, 0);
        }
    }

    // ---- tail: 16 new rows (t = LC..LC+15), all waves (own heads), causal
    if (chunk == NCH - 1) {
        __syncthreads();
        #pragma unroll
        for (int q = 0; q < 4; ++q) {
            int idx = tid + q * 256;               // 16 rows x 64 chunks
            int rr = idx >> 6, ch = idx & 63;
            size_t off = ((size_t)(LC + rr)) * 8192 + (size_t)b * 1024 + hg * 256 + ch * 4;
            float4 k4 = *(const float4*)(newk + off);
            float4 v4 = *(const float4*)(newv + off);
            int w = ch >> 4, cc = ch & 15;
            int kidx = rr * 256 + w * 64 + ((cc * 4) ^ ((rr & 7) << 3));
            *(s4v*)(Ksp + kidx) = pack4(k4.x, k4.y, k4.z, k4.w);
            int vidx = w * 2080 + (cc >> 2) * 520 + (rr >> 2) * 64 + (rr & 3) * 16 + (cc & 3) * 4;
            *(s4v*)(Vp + vidx) = pack4(v4.x, v4.y, v4.z, v4.w);
        }
        __syncthreads();
        f4 d0 = {0,0,0,0};
        #pragma unroll
        for (int sl = 0; sl < 2; ++sl) {
            int col = (sl * 32 + g * 8) ^ sw;
            s8v k0 = *(const s8v*)(Ksp + c16 * 256 + wid * 64 + col);
            d0 = __builtin_amdgcn_mfma_f32_16x16x32_bf16(k0, qf[sl], d0, 0, 0, 0);
        }
        #pragma unroll
        for (int r = 0; r < 4; ++r)
            if (4 * g + r > c16) d0[r] = -1e30f;   // causal: t > s
        float hm = fmaxf(fmaxf(d0[0], d0[1]), fmaxf(d0[2], d0[3]));
        hm = fmaxf(hm, __shfl_xor(hm, 16));
        hm = fmaxf(hm, __shfl_xor(hm, 32));
        float mn = fmaxf(m_prev, hm);
        float sf = __expf(m_prev - mn);
        m_prev = mn;
        f4 p0;
        #pragma unroll
        for (int r = 0; r < 4; ++r) p0[r] = __expf(d0[r] - mn);
        float rs = (p0[0] + p0[1]) + (p0[2] + p0[3]);
        rs += __shfl_xor(rs, 16);
        rs += __shfl_xor(rs, 32);
        l_acc = l_acc * sf + rs;
        #pragma unroll
        for (int dd = 0; dd < 4; ++dd) acc[dd] *= sf;
        s4v pb0 = pack4(p0[0], p0[1], p0[2], p0[3]);
        s4v vfr[4];
        #pragma unroll
        for (int dd = 0; dd < 4; ++dd) {
            unsigned adr = vbase + 2u * (unsigned)(dd * 520 + g * 64 + c16);
            asm volatile("ds_read_b64_tr_b16 %0, %1" : "=v"(vfr[dd]) : "v"(adr));
        }
        asm volatile("s_waitcnt lgkmcnt(0)" ::: "memory");
        __builtin_amdgcn_sched_barrier(0);
        #pragma unroll
        for (int dd = 0; dd < 4; ++dd)
            acc[dd] = __builtin_amdgcn_mfma_f32_16x16x16bf16_1k(vfr[dd], pb0, acc[dd], 0, 0, 0);
    }

    // ---- emit per-wave (= per-head) partials directly --------------------
    int pi = ((b * 16 + h) * NCH) + chunk;
    #pragma unroll
    for (int dd = 0; dd < 4; ++dd)
        #pragma unroll
        for (int r = 0; r < 4; ++r)
            pv_part[((size_t)pi * 64 + dd * 16 + g * 4 + r) * 16 + c16] = acc[dd][r];
    if (l < 16) {
        m_part[pi * 16 + l] = m_prev;
        l_part[pi * 16 + l] = l_acc;
    }
}

// ---- combine 32 chunk-partials -> ctx -------------------------------------
// grid = B*H (bh), block = 256
__global__ __launch_bounds__(256) void combine(const float* __restrict__ m_part,
        const float* __restrict__ l_part, const float* __restrict__ pv_part,
        float* __restrict__ ctx)
{
    __shared__ float wexp[NCH][16];
    __shared__ float Ls[16];
    int bh = blockIdx.x;
    int h = bh & 15, b = bh >> 4;
    int tid = threadIdx.x;
    if (tid < 16) {
        int s = tid;
        float M = -1e30f;
        #pragma unroll
        for (int c = 0; c < NCH; ++c) M = fmaxf(M, m_part[(bh * NCH + c) * 16 + s]);
        float L = 0.f;
        #pragma unroll
        for (int c = 0; c < NCH; ++c) {
            float e = __expf(m_part[(bh * NCH + c) * 16 + s] - M);
            wexp[c][s] = e;
            L += e * l_part[(bh * NCH + c) * 16 + s];
        }
        Ls[s] = L;
    }
    __syncthreads();
    #pragma unroll
    for (int k = 0; k < 4; ++k) {
        int idx = tid + k * 256;
        int d = idx >> 4, s = idx & 15;
        float v = 0.f;
        #pragma unroll
        for (int c = 0; c < NCH; ++c)
            v += wexp[c][s] * pv_part[((size_t)(bh * NCH + c) * 64 + d) * 16 + s];
        ctx[((size_t)(s * B + b)) * HD + h * DH + d] = v / Ls[s];
    }
}

// ---- output projection (R5, proven): 4 rows/block -------------------------
__global__ __launch_bounds__(256) void proj_o(const float* __restrict__ ctx,
                                              const float* __restrict__ Wo,
                                              float* __restrict__ res)
{
    int bx = blockIdx.x;
    int rg = bx >> 2, chunk = bx & 3;
    int o = chunk * 256 + threadIdx.x;
    const float* cr = ctx + (size_t)rg * 4 * HD;

    float a0 = 0.f, a1 = 0.f, a2 = 0.f, a3 = 0.f;
    #pragma unroll 16
    for (int d = 0; d < HD; ++d) {
        float w = Wo[(size_t)d * D + o];
        a0 += cr[d] * w;
        a1 += cr[HD + d] * w;
        a2 += cr[2 * HD + d] * w;
        a3 += cr[3 * HD + d] * w;
    }
    res[(size_t)(rg * 4 + 0) * D + o] = a0;
    res[(size_t)(rg * 4 + 1) * D + o] = a1;
    res[(size_t)(rg * 4 + 2) * D + o] = a2;
    res[(size_t)(rg * 4 + 3) * D + o] = a3;
}

extern "C" void kernel_launch(void* const* d_in, const int* in_sizes, int n_in,
                              void* d_out, int out_size, void* d_ws, size_t ws_size,
                              hipStream_t stream)
{
    const float* x  = (const float*)d_in[0];
    const float* ck = (const float*)d_in[1];
    const float* cv = (const float*)d_in[2];
    const float* Wq = (const float*)d_in[3];
    const float* Wk = (const float*)d_in[4];
    const float* Wv = (const float*)d_in[5];
    const float* Wo = (const float*)d_in[6];

    float* out  = (float*)d_out;
    float* res  = out;                                   // (S,B,D)
    float* newk = out + (size_t)S * B * D;               // (L,B,H,DH)
    float* newv = newk + (size_t)LMAX * B * H * DH;

    float* q_ws    = (float*)d_ws;                               // 131072 f
    float* ctx     = q_ws + (size_t)S * B * HD;                  // 131072 f
    float* m_part  = ctx + (size_t)S * B * HD;                   // 4096*16 f
    float* l_part  = m_part + (size_t)B * H * NCH * S;           // 4096*16 f
    float* pv_part = l_part + (size_t)B * H * NCH * S;           // 4096*1024 f

    size_t smem = (size_t)TILE * 256 * 2 + 4 * 2080 * 2;         // 33024 B

    hipLaunchKernelGGL(proj_qkv, dim3(32 * 12), dim3(256), 0, stream,
                       x, Wq, Wk, Wv, q_ws, newk, newv);
    hipLaunchKernelGGL(attn_fused, dim3(B * 4 * NCH), dim3(256), smem, stream,
                       q_ws, ck, cv, newk, newv, m_part, l_part, pv_part);
    hipLaunchKernelGGL(combine, dim3(B * H), dim3(256), 0, stream,
                       m_part, l_part, pv_part, ctx);
    hipLaunchKernelGGL(proj_o, dim3(32 * 4), dim3(256), 0, stream,
                       ctx, Wo, res);
}

// Round 11
// 295.410 us; speedup vs baseline: 2.1543x; 1.2142x over previous
//
#include <hip/hip_runtime.h>
#include <hip/hip_bf16.h>

#define S 16
#define B 8
#define H 16
#define DH 64
#define D 1024
#define HD 1024          // H*DH
#define LC 8192
#define LMAX (LC + S)    // 8208
#define NCH 32           // L-chunks per (b,hg)
#define CHT 256          // t rows per chunk
#define TILE 16          // rows staged per iteration
#define NT (CHT / TILE)  // 16

typedef __attribute__((ext_vector_type(4))) float f4;
typedef __attribute__((ext_vector_type(4))) short s4v;
typedef __attribute__((ext_vector_type(8))) short s8v;

__device__ inline short bfs(float f) {
    __hip_bfloat16 h = __float2bfloat16(f);   // RNE; pairs fuse to cvt_pk
    return __builtin_bit_cast(short, h);
}
__device__ inline s4v pack4(float a, float b, float c, float d) {
    s4v r; r[0] = bfs(a); r[1] = bfs(b); r[2] = bfs(c); r[3] = bfs(d); return r;
}

// ---- QKV projection (R5, proven) + res zeroing ----------------------------
__global__ __launch_bounds__(256) void proj_qkv(const float* __restrict__ x,
        const float* __restrict__ Wq, const float* __restrict__ Wk,
        const float* __restrict__ Wv,
        float* __restrict__ q_ws, float* __restrict__ newk, float* __restrict__ newv,
        float* __restrict__ res)
{
    int bx = blockIdx.x;
    int rg  = bx / 12;
    int rem = bx % 12;
    int mat = rem >> 2, chunk = rem & 3;
    int o = chunk * 256 + threadIdx.x;
    const float* W  = (mat == 0) ? Wq : ((mat == 1) ? Wk : Wv);
    const float* xr = x + (size_t)rg * 4 * D;

    float a0 = 0.f, a1 = 0.f, a2 = 0.f, a3 = 0.f;
    #pragma unroll 16
    for (int d = 0; d < D; ++d) {
        float w = W[(size_t)d * HD + o];
        a0 += xr[d] * w;
        a1 += xr[D + d] * w;
        a2 += xr[2 * D + d] * w;
        a3 += xr[3 * D + d] * w;
    }
    float acc[4] = {a0, a1, a2, a3};
    #pragma unroll
    for (int i = 0; i < 4; ++i) {
        int row = rg * 4 + i;
        int s = row >> 3, b = row & 7;
        if (mat == 0) {
            q_ws[(size_t)row * HD + o] = acc[i];
            res[(size_t)row * D + o] = 0.f;      // zero res for combine_proj atomics
        } else {
            float* dst = (mat == 1) ? newk : newv;
            dst[(size_t)((LC + s) * B + b) * HD + o] = acc[i];
        }
    }
}

// ---- fused cache-copy + MFMA flash attention, reg-prefetch pipelined ------
// grid = B*4*NCH: chunk (0..31) fastest, then hg (0..3), b (0..7).
// TILE=16 rows x [4 heads x 64 dh] = 1KB-contiguous rows. Wave wid owns head hg*4+wid.
// Register double-buffer: tile it+1's loads issued a full iteration before use.
__global__ __launch_bounds__(256, 4) void attn_fused(const float* __restrict__ q_ws,
        const float* __restrict__ cache_k, const float* __restrict__ cache_v,
        float* __restrict__ newk, float* __restrict__ newv,
        float* __restrict__ m_part, float* __restrict__ l_part,
        float* __restrict__ pv_part)
{
    extern __shared__ char smem[];
    short* Ksp = (short*)smem;            // [16][256] bf16, XOR-swz per 64-elem head slice (8KB)
    short* Vp  = Ksp + TILE * 256;        // 4 heads x (4 dd x 264) subtiled V (8448B)

    int bx = blockIdx.x;
    int chunk = bx & 31;
    int hgb = bx >> 5;
    int hg = hgb & 3, b = hgb >> 2;
    int tid = threadIdx.x, l = tid & 63, wid = tid >> 6;
    int g = l >> 4, c16 = l & 15;
    int h = hg * 4 + wid;
    int rrb = tid >> 6, ch = tid & 63;    // stage: row-base, 16B-chunk in 1KB row
    int w = ch >> 4, cc = ch & 15;
    unsigned vbase = (unsigned)(uintptr_t)Vp + (unsigned)wid * 2112u;

    // Q fragments for head h
    s8v qf[2];
    {
        const float* qp = q_ws + ((size_t)(c16 * B + b)) * HD + h * DH + g * 8;
        #pragma unroll
        for (int sl = 0; sl < 2; ++sl) {
            float4 qa = *(const float4*)(qp + sl * 32);
            float4 qb = *(const float4*)(qp + sl * 32 + 4);
            s8v q;
            q[0] = bfs(qa.x * 0.125f); q[1] = bfs(qa.y * 0.125f);
            q[2] = bfs(qa.z * 0.125f); q[3] = bfs(qa.w * 0.125f);
            q[4] = bfs(qb.x * 0.125f); q[5] = bfs(qb.y * 0.125f);
            q[6] = bfs(qb.z * 0.125f); q[7] = bfs(qb.w * 0.125f);
            qf[sl] = q;
        }
    }

    float m_prev = -1e30f, l_acc = 0.f;
    f4 acc[4] = {{0,0,0,0},{0,0,0,0},{0,0,0,0},{0,0,0,0}};

    int t0base = chunk * CHT;
    int sw = (c16 & 7) << 3;
    size_t cbase = (size_t)b * 1024 + hg * 256 + ch * 4;

    // prologue: prefetch tile 0
    f4 kb[2][4], vb[2][4];
    #pragma unroll
    for (int gg = 0; gg < 4; ++gg) {
        size_t off = ((size_t)(t0base + rrb + 4 * gg)) * 8192 + cbase;
        kb[0][gg] = __builtin_nontemporal_load((const f4*)(cache_k + off));
        vb[0][gg] = __builtin_nontemporal_load((const f4*)(cache_v + off));
    }

    #pragma unroll
    for (int it = 0; it < NT; ++it) {
        const int cur = it & 1, nxt = cur ^ 1;
        int t0 = t0base + it * TILE;

        // issue next tile's loads (stay in flight across barriers + compute)
        if (it + 1 < NT) {
            #pragma unroll
            for (int gg = 0; gg < 4; ++gg) {
                size_t off = ((size_t)(t0 + TILE + rrb + 4 * gg)) * 8192 + cbase;
                kb[nxt][gg] = __builtin_nontemporal_load((const f4*)(cache_k + off));
                vb[nxt][gg] = __builtin_nontemporal_load((const f4*)(cache_v + off));
            }
        }
        // barrier 1: previous tile's LDS readers done (lgkm only)
        asm volatile("s_waitcnt lgkmcnt(0)" ::: "memory");
        __builtin_amdgcn_s_barrier();
        __builtin_amdgcn_sched_barrier(0);

        // stage cur tile: fp32 copy out, bf16 into LDS (K swz, V subtiled)
        #pragma unroll
        for (int gg = 0; gg < 4; ++gg) {
            int rr = rrb + 4 * gg;
            size_t off = ((size_t)(t0 + rr)) * 8192 + cbase;
            __builtin_nontemporal_store(kb[cur][gg], (f4*)(newk + off));
            __builtin_nontemporal_store(vb[cur][gg], (f4*)(newv + off));
            int kidx = rr * 256 + w * 64 + ((cc * 4) ^ ((rr & 7) << 3));
            *(s4v*)(Ksp + kidx) = pack4(kb[cur][gg][0], kb[cur][gg][1], kb[cur][gg][2], kb[cur][gg][3]);
            int vidx = w * 1056 + (cc >> 2) * 264 + (rr >> 2) * 64 + (rr & 3) * 16 + (cc & 3) * 4;
            *(s4v*)(Vp + vidx) = pack4(vb[cur][gg][0], vb[cur][gg][1], vb[cur][gg][2], vb[cur][gg][3]);
        }
        // barrier 2: staging ds_writes visible (lgkm only; stores/loads in flight)
        asm volatile("s_waitcnt lgkmcnt(0)" ::: "memory");
        __builtin_amdgcn_s_barrier();
        __builtin_amdgcn_sched_barrier(0);

        // QK^T: D[t][s] for this head's 16 rows
        f4 d0 = {0,0,0,0};
        #pragma unroll
        for (int sl = 0; sl < 2; ++sl) {
            int col = (sl * 32 + g * 8) ^ sw;
            s8v k0 = *(const s8v*)(Ksp + c16 * 256 + wid * 64 + col);
            d0 = __builtin_amdgcn_mfma_f32_16x16x32_bf16(k0, qf[sl], d0, 0, 0, 0);
        }
        // online softmax (per-lane state for s = c16)
        float hm = fmaxf(fmaxf(d0[0], d0[1]), fmaxf(d0[2], d0[3]));
        hm = fmaxf(hm, __shfl_xor(hm, 16));
        hm = fmaxf(hm, __shfl_xor(hm, 32));
        float mn = fmaxf(m_prev, hm);
        float sf = __expf(m_prev - mn);
        m_prev = mn;
        f4 p0;
        #pragma unroll
        for (int r = 0; r < 4; ++r) p0[r] = __expf(d0[r] - mn);
        float rs = (p0[0] + p0[1]) + (p0[2] + p0[3]);
        rs += __shfl_xor(rs, 16);
        rs += __shfl_xor(rs, 32);
        l_acc = l_acc * sf + rs;
        #pragma unroll
        for (int dd = 0; dd < 4; ++dd) acc[dd] *= sf;

        // PV: A = V^T via tr-reads, B = P
        s4v pb0 = pack4(p0[0], p0[1], p0[2], p0[3]);
        s4v vfr[4];
        #pragma unroll
        for (int dd = 0; dd < 4; ++dd) {
            unsigned adr = vbase + 2u * (unsigned)(dd * 264 + g * 64 + c16);
            asm volatile("ds_read_b64_tr_b16 %0, %1" : "=v"(vfr[dd]) : "v"(adr));
        }
        asm volatile("s_waitcnt lgkmcnt(0)" ::: "memory");
        __builtin_amdgcn_sched_barrier(0);
        #pragma unroll
        for (int dd = 0; dd < 4; ++dd)
            acc[dd] = __builtin_amdgcn_mfma_f32_16x16x16bf16_1k(vfr[dd], pb0, acc[dd], 0, 0, 0);
    }

    // tail: 16 new rows (t = LC..LC+15), causal-masked
    if (chunk == NCH - 1) {
        __syncthreads();
        #pragma unroll
        for (int q = 0; q < 4; ++q) {
            int idx = tid + q * 256;
            int rr = idx >> 6, c2 = idx & 63;
            int w2 = c2 >> 4, cc2 = c2 & 15;
            size_t off = ((size_t)(LC + rr)) * 8192 + (size_t)b * 1024 + hg * 256 + c2 * 4;
            float4 k4 = *(const float4*)(newk + off);
            float4 v4 = *(const float4*)(newv + off);
            int kidx = rr * 256 + w2 * 64 + ((cc2 * 4) ^ ((rr & 7) << 3));
            *(s4v*)(Ksp + kidx) = pack4(k4.x, k4.y, k4.z, k4.w);
            int vidx = w2 * 1056 + (cc2 >> 2) * 264 + (rr >> 2) * 64 + (rr & 3) * 16 + (cc2 & 3) * 4;
            *(s4v*)(Vp + vidx) = pack4(v4.x, v4.y, v4.z, v4.w);
        }
        __syncthreads();
        f4 d0 = {0,0,0,0};
        #pragma unroll
        for (int sl = 0; sl < 2; ++sl) {
            int col = (sl * 32 + g * 8) ^ sw;
            s8v k0 = *(const s8v*)(Ksp + c16 * 256 + wid * 64 + col);
            d0 = __builtin_amdgcn_mfma_f32_16x16x32_bf16(k0, qf[sl], d0, 0, 0, 0);
        }
        #pragma unroll
        for (int r = 0; r < 4; ++r)
            if (4 * g + r > c16) d0[r] = -1e30f;   // causal: t > s
        float hm = fmaxf(fmaxf(d0[0], d0[1]), fmaxf(d0[2], d0[3]));
        hm = fmaxf(hm, __shfl_xor(hm, 16));
        hm = fmaxf(hm, __shfl_xor(hm, 32));
        float mn = fmaxf(m_prev, hm);
        float sf = __expf(m_prev - mn);
        m_prev = mn;
        f4 p0;
        #pragma unroll
        for (int r = 0; r < 4; ++r) p0[r] = __expf(d0[r] - mn);
        float rs = (p0[0] + p0[1]) + (p0[2] + p0[3]);
        rs += __shfl_xor(rs, 16);
        rs += __shfl_xor(rs, 32);
        l_acc = l_acc * sf + rs;
        #pragma unroll
        for (int dd = 0; dd < 4; ++dd) acc[dd] *= sf;
        s4v pb0 = pack4(p0[0], p0[1], p0[2], p0[3]);
        s4v vfr[4];
        #pragma unroll
        for (int dd = 0; dd < 4; ++dd) {
            unsigned adr = vbase + 2u * (unsigned)(dd * 264 + g * 64 + c16);
            asm volatile("ds_read_b64_tr_b16 %0, %1" : "=v"(vfr[dd]) : "v"(adr));
        }
        asm volatile("s_waitcnt lgkmcnt(0)" ::: "memory");
        __builtin_amdgcn_sched_barrier(0);
        #pragma unroll
        for (int dd = 0; dd < 4; ++dd)
            acc[dd] = __builtin_amdgcn_mfma_f32_16x16x16bf16_1k(vfr[dd], pb0, acc[dd], 0, 0, 0);
    }

    // emit per-wave (= per-head) partials
    int pi = ((b * 16 + h) * NCH) + chunk;
    #pragma unroll
    for (int dd = 0; dd < 4; ++dd)
        #pragma unroll
        for (int r = 0; r < 4; ++r)
            pv_part[((size_t)pi * 64 + dd * 16 + g * 4 + r) * 16 + c16] = acc[dd][r];
    if (l < 16) {
        m_part[pi * 16 + l] = m_prev;
        l_part[pi * 16 + l] = l_acc;
    }
}

// ---- fused combine + output projection ------------------------------------
// grid = B*H*4 (bh*4 + oc), block = 256; atomicAdd into res (zeroed by proj_qkv)
__global__ __launch_bounds__(256) void combine_proj(const float* __restrict__ m_part,
        const float* __restrict__ l_part, const float* __restrict__ pv_part,
        const float* __restrict__ Wo, float* __restrict__ res)
{
    __shared__ float wexp[NCH][16];
    __shared__ float Ls[16];
    __shared__ float cds[64][16];          // ctx^T [d][s] for this (b,h)
    int bx = blockIdx.x;
    int oc = bx & 3, bh = bx >> 2;
    int h = bh & 15, b = bh >> 4;
    int tid = threadIdx.x;

    if (tid < 16) {
        int s = tid;
        float M = -1e30f;
        #pragma unroll
        for (int c = 0; c < NCH; ++c) M = fmaxf(M, m_part[(bh * NCH + c) * 16 + s]);
        float L = 0.f;
        #pragma unroll
        for (int c = 0; c < NCH; ++c) {
            float e = __expf(m_part[(bh * NCH + c) * 16 + s] - M);
            wexp[c][s] = e;
            L += e * l_part[(bh * NCH + c) * 16 + s];
        }
        Ls[s] = L;
    }
    __syncthreads();
    #pragma unroll
    for (int k = 0; k < 4; ++k) {
        int idx = tid + k * 256;
        int d = idx >> 4, s = idx & 15;
        float v = 0.f;
        #pragma unroll
        for (int c = 0; c < NCH; ++c)
            v += wexp[c][s] * pv_part[((size_t)(bh * NCH + c) * 64 + d) * 16 + s];
        cds[d][s] = v / Ls[s];
    }
    __syncthreads();

    int o = oc * 256 + tid;
    float acc[16];
    #pragma unroll
    for (int s = 0; s < 16; ++s) acc[s] = 0.f;
    #pragma unroll 8
    for (int d = 0; d < 64; ++d) {
        float wv = Wo[(size_t)(h * 64 + d) * D + o];
        #pragma unroll
        for (int q = 0; q < 4; ++q) {
            f4 cq = *(const f4*)&cds[d][q * 4];   // broadcast reads
            acc[q * 4 + 0] += cq[0] * wv;
            acc[q * 4 + 1] += cq[1] * wv;
            acc[q * 4 + 2] += cq[2] * wv;
            acc[q * 4 + 3] += cq[3] * wv;
        }
    }
    #pragma unroll
    for (int s = 0; s < 16; ++s)
        atomicAdd(res + (size_t)(s * B + b) * D + o, acc[s]);
}

extern "C" void kernel_launch(void* const* d_in, const int* in_sizes, int n_in,
                              void* d_out, int out_size, void* d_ws, size_t ws_size,
                              hipStream_t stream)
{
    const float* x  = (const float*)d_in[0];
    const float* ck = (const float*)d_in[1];
    const float* cv = (const float*)d_in[2];
    const float* Wq = (const float*)d_in[3];
    const float* Wk = (const float*)d_in[4];
    const float* Wv = (const float*)d_in[5];
    const float* Wo = (const float*)d_in[6];

    float* out  = (float*)d_out;
    float* res  = out;                                   // (S,B,D)
    float* newk = out + (size_t)S * B * D;               // (L,B,H,DH)
    float* newv = newk + (size_t)LMAX * B * H * DH;

    float* q_ws    = (float*)d_ws;                               // 131072 f
    float* ctx     = q_ws + (size_t)S * B * HD;                  // (unused, layout kept)
    float* m_part  = ctx + (size_t)S * B * HD;                   // 4096*16 f
    float* l_part  = m_part + (size_t)B * H * NCH * S;           // 4096*16 f
    float* pv_part = l_part + (size_t)B * H * NCH * S;           // 4096*1024 f

    size_t smem = (size_t)(TILE * 256 + 4 * 1056) * 2;           // 16640 B

    hipLaunchKernelGGL(proj_qkv, dim3(32 * 12), dim3(256), 0, stream,
                       x, Wq, Wk, Wv, q_ws, newk, newv, res);
    hipLaunchKernelGGL(attn_fused, dim3(B * 4 * NCH), dim3(256), smem, stream,
                       q_ws, ck, cv, newk, newv, m_part, l_part, pv_part);
    hipLaunchKernelGGL(combine_proj, dim3(B * H * 4), dim3(256), 0, stream,
                       m_part, l_part, pv_part, Wo, res);
}